// Round 6
// baseline (398.738 us; speedup 1.0000x reference)
//
#include <hip/hip_runtime.h>
#include <hip/hip_bf16.h>
#include <stdint.h>

#define LL 2048
#define BB 8
#define NNODE 16384           // BB*LL
#define HID 512
#define KNN_K 10
#define NEDGE (NNODE * KNN_K) // 163840
#define BN_EPS 1e-5f

typedef __attribute__((ext_vector_type(4))) float f32x4;
typedef __attribute__((ext_vector_type(8))) short short8;
typedef __attribute__((ext_vector_type(8))) __bf16 bf16x8;
typedef unsigned long long u64;

__device__ __forceinline__ unsigned short f2bf(float f) {
  unsigned u = __float_as_uint(f);
  u += 0x7FFFu + ((u >> 16) & 1u);   // RNE
  return (unsigned short)(u >> 16);
}
__device__ __forceinline__ float bf2f(unsigned short u) {
  return __uint_as_float(((unsigned)u) << 16);
}

__device__ __forceinline__ void gload_lds16(const void* g, void* l) {
  __builtin_amdgcn_global_load_lds((const __attribute__((address_space(1))) void*)g,
                                   (__attribute__((address_space(3))) void*)l, 16, 0, 0);
}

__device__ __forceinline__ f32x4 mfma_bf16(short8 a, short8 b, f32x4 c) {
  return __builtin_amdgcn_mfma_f32_16x16x32_bf16(
      __builtin_bit_cast(bf16x8, a), __builtin_bit_cast(bf16x8, b), c, 0, 0, 0);
}

// wave-wide min of u64 key: xor strides 1..16 via ds_swizzle (no addr VALU), 32 via shfl
// (R3-proven verbatim)
__device__ __forceinline__ u64 wave_min_u64(u64 v) {
#define SWZ_STEP(pat)                                                   \
  {                                                                     \
    unsigned lo = (unsigned)v, hi = (unsigned)(v >> 32);                \
    unsigned slo = (unsigned)__builtin_amdgcn_ds_swizzle((int)lo, pat); \
    unsigned shi = (unsigned)__builtin_amdgcn_ds_swizzle((int)hi, pat); \
    u64 o = (((u64)shi) << 32) | slo;                                   \
    if (o < v) v = o;                                                   \
  }
  SWZ_STEP(0x041F)  // xor 1
  SWZ_STEP(0x081F)  // xor 2
  SWZ_STEP(0x101F)  // xor 4
  SWZ_STEP(0x201F)  // xor 8
  SWZ_STEP(0x401F)  // xor 16
#undef SWZ_STEP
  {
    u64 o = __shfl_xor(v, 32, 64);
    if (o < v) v = o;
  }
  return v;
}

// ---------------- coords AoS -> SoA ----------------
__global__ __launch_bounds__(256) void soa_kernel(const float* __restrict__ ca,
                                                  float* __restrict__ cs) {
  const int i = blockIdx.x * 256 + threadIdx.x;
  cs[i] = ca[(size_t)i * 3 + 0];
  cs[NNODE + i] = ca[(size_t)i * 3 + 1];
  cs[2 * NNODE + i] = ca[(size_t)i * 3 + 2];
}

// ---------------- kNN (R3-exact, passed twice): 32 resident u64 keys; 10 rounds ----------------
__global__ __launch_bounds__(256) void knn_kernel(const float* __restrict__ cs,
                                                  int* __restrict__ knn_out) {
  const int node = blockIdx.x * 4 + (threadIdx.x >> 6);
  const int lane = threadIdx.x & 63;
  const int b = node >> 11;
  const int il = node & (LL - 1);
  const int boff = b << 11;
  const float* __restrict__ X = cs + boff;
  const float* __restrict__ Y = cs + NNODE + boff;
  const float* __restrict__ Z = cs + 2 * NNODE + boff;
  const float cx = X[il], cy = Y[il], cz = Z[il];
  u64 key[32];
#pragma unroll
  for (int jj = 0; jj < 32; ++jj) {
    const int j = jj * 64 + lane;
    // match numpy: ((dx^2 + dy^2) + dz^2), no fma contraction
    float dx = __fsub_rn(cx, X[j]);
    float dy = __fsub_rn(cy, Y[j]);
    float dz = __fsub_rn(cz, Z[j]);
    float s = __fmul_rn(dx, dx);
    s = __fadd_rn(s, __fmul_rn(dy, dy));
    s = __fadd_rn(s, __fmul_rn(dz, dz));
    key[jj] = (((u64)__float_as_uint(s)) << 32) | (unsigned)j;
  }
  // self has d2 == 0.0 exactly -> rank-0; start strictly after it.
  u64 last = (u64)(unsigned)il;
#pragma unroll 1
  for (int r = 0; r < KNN_K; ++r) {
    u64 b0 = ~0ull, b1 = ~0ull, b2 = ~0ull, b3 = ~0ull;
#pragma unroll
    for (int jj = 0; jj < 32; jj += 4) {
      { u64 k = key[jj + 0]; if (k > last && k < b0) b0 = k; }
      { u64 k = key[jj + 1]; if (k > last && k < b1) b1 = k; }
      { u64 k = key[jj + 2]; if (k > last && k < b2) b2 = k; }
      { u64 k = key[jj + 3]; if (k > last && k < b3) b3 = k; }
    }
    b0 = b0 < b1 ? b0 : b1;
    b2 = b2 < b3 ? b2 : b3;
    u64 best = wave_min_u64(b0 < b2 ? b0 : b2);
    if (lane == 0) knn_out[node * KNN_K + r] = boff + (int)(unsigned)best;
    last = best;
  }
}

// ---------------- reverse-CSR build (R3-exact) ----------------
__global__ void csr_count_kernel(const int* __restrict__ knn, int* __restrict__ cnt) {
  int e = blockIdx.x * 256 + threadIdx.x;
  atomicAdd(&cnt[knn[e]], 1);
}

__global__ __launch_bounds__(1024) void csr_scan_kernel(const int* __restrict__ cnt,
                                                        int* __restrict__ off) {
  __shared__ int part[1024];
  const int t = threadIdx.x;
  int loc[16];
  int s = 0;
#pragma unroll
  for (int k = 0; k < 16; ++k) { loc[k] = s; s += cnt[t * 16 + k]; }
  part[t] = s;
  __syncthreads();
  for (int d = 1; d < 1024; d <<= 1) {
    int v = (t >= d) ? part[t - d] : 0;
    __syncthreads();
    part[t] += v;
    __syncthreads();
  }
  int base = (t == 0) ? 0 : part[t - 1];
#pragma unroll
  for (int k = 0; k < 16; ++k) off[t * 16 + k] = base + loc[k];
  if (t == 1023) off[NNODE] = base + s;
}

__global__ void csr_fill_kernel(const int* __restrict__ knn, const int* __restrict__ off,
                                int* __restrict__ cur, int* __restrict__ lst) {
  int e = blockIdx.x * 256 + threadIdx.x;
  int dst = knn[e];
  int p = atomicAdd(&cur[dst], 1);
  lst[off[dst] + p] = e / KNN_K;   // src node (global id)
}

// ---------------- layer 1 (din=3): direct 9-wide dot, one wave per node; bf16 out ----------------
__global__ __launch_bounds__(256) void layer1_kernel(
    const float* __restrict__ ca, const int* __restrict__ roff, const int* __restrict__ rlist,
    const float* __restrict__ W1, const float* __restrict__ b1, const float* __restrict__ Wsl1,
    const float* __restrict__ bsl1, const float* __restrict__ gamma,
    const float* __restrict__ beta, const float* __restrict__ mean, const float* __restrict__ var,
    unsigned short* __restrict__ h) {
  const int node = blockIdx.x * 4 + (threadIdx.x >> 6);
  const int lane = threadIdx.x & 63;
  const int b = node >> 11;
  const int il = node & (LL - 1);
  const float* __restrict__ cb = ca + (size_t)b * LL * 3;
  float sx = 0, sy = 0, sz = 0;
#pragma unroll
  for (int d = -3; d <= 3; ++d) {
    if (d == 0) continue;
    int j = il + d;
    if ((unsigned)j < LL) { sx += cb[j * 3]; sy += cb[j * 3 + 1]; sz += cb[j * 3 + 2]; }
  }
  float kx = 0, ky = 0, kz = 0;
  const int e1 = roff[node + 1];
  for (int e = roff[node]; e < e1; ++e) {
    int si = rlist[e];
    kx += ca[si * 3]; ky += ca[si * 3 + 1]; kz += ca[si * 3 + 2];
  }
  const float xx = cb[il * 3], xy = cb[il * 3 + 1], xz = cb[il * 3 + 2];
#pragma unroll
  for (int r = 0; r < 8; ++r) {
    const int n = lane + 64 * r;
    const float* wr = W1 + n * 21;   // rel0 cols 0..2, rel2 cols 6..8
    const float* wsl = Wsl1 + n * 3;
    float acc = sx * wr[0] + sy * wr[1] + sz * wr[2] + kx * wr[6] + ky * wr[7] + kz * wr[8] +
                xx * wsl[0] + xy * wsl[1] + xz * wsl[2] + b1[n] + bsl1[n];
    float scl = gamma[n] * rsqrtf(var[n] + BN_EPS);
    float o2 = (acc - mean[n]) * scl + beta[n];
    h[(size_t)node * HID + n] = f2bf(o2 > 0.f ? o2 : 0.f);
  }
}

// ---------------- weight prep: Wcat = [W_rel0 | W_rel2 | Wsl] bf16, BN scale/shift ----------------
__global__ void prep_weights_kernel(const float* __restrict__ Ws, const float* __restrict__ bs,
                                    const float* __restrict__ Wsls, const float* __restrict__ bsls,
                                    const float* __restrict__ gam, const float* __restrict__ bet,
                                    const float* __restrict__ mea, const float* __restrict__ va,
                                    unsigned short* __restrict__ Wcat, float* __restrict__ sc,
                                    float* __restrict__ sh) {
  const int idx = blockIdx.x * 256 + threadIdx.x;
  if (idx >= 3 * 512 * 1536) return;
  const int l = idx / (512 * 1536);
  const int rem = idx - l * (512 * 1536);
  const int n = rem / 1536;
  const int k = rem - n * 1536;
  float v;
  if (k < 512)
    v = Ws[(size_t)l * 512 * 3584 + (size_t)n * 3584 + k];                // rel 0
  else if (k < 1024)
    v = Ws[(size_t)l * 512 * 3584 + (size_t)n * 3584 + 1024 + (k - 512)]; // rel 2
  else
    v = Wsls[(size_t)l * 512 * 512 + (size_t)n * 512 + (k - 1024)];       // self-loop
  Wcat[idx] = f2bf(v);
  if (k == 0) {
    const int g = (l + 1) * 512 + n;
    float s = gam[g] * rsqrtf(va[g] + BN_EPS);
    sc[l * 512 + n] = s;
    sh[l * 512 + n] = bet[g] + (bs[l * 512 + n] + bsls[l * 512 + n] - mea[g]) * s;
  }
}

// ---------------- aggregation: U[i] = [seq_sum | knn_sum] bf16 (x-part staged from h in gemm) ---
// XCD-affinity: batch b (2 MB h-slab) pinned to XCD b via blockIdx%8 -> gathers hit local L2.
__global__ __launch_bounds__(256) void agg_kernel(const unsigned short* __restrict__ hb,
                                                  const int* __restrict__ roff,
                                                  const int* __restrict__ rlist,
                                                  unsigned short* __restrict__ U) {
  const int g = blockIdx.x;   // 4096 blocks, 4 nodes each (one wave per node)
  const int node = ((g & 7) << 11) | ((g >> 3) << 2) | (threadIdx.x >> 6);
  const int lane = threadIdx.x & 63;
  const int b = node >> 11;
  const int il = node & (LL - 1);
  float sq[8] = {}, kq[8] = {};
  const int offs[6] = {-3, -2, -1, 1, 2, 3};
#pragma unroll
  for (int q = 0; q < 6; ++q) {
    int j = il + offs[q];
    if ((unsigned)j < LL) {
      short8 v = *reinterpret_cast<const short8*>(&hb[(size_t)(b * LL + j) * HID + lane * 8]);
#pragma unroll
      for (int e = 0; e < 8; ++e) sq[e] += bf2f((unsigned short)v[e]);
    }
  }
  const int e1 = roff[node + 1];
  for (int e = roff[node]; e < e1; ++e) {
    short8 v = *reinterpret_cast<const short8*>(&hb[(size_t)rlist[e] * HID + lane * 8]);
#pragma unroll
    for (int q = 0; q < 8; ++q) kq[q] += bf2f((unsigned short)v[q]);
  }
  unsigned short* Ur = U + (size_t)node * 1024;
  short8 o;
#pragma unroll
  for (int e = 0; e < 8; ++e) o[e] = (short)f2bf(sq[e]);
  *reinterpret_cast<short8*>(&Ur[lane * 8]) = o;
#pragma unroll
  for (int e = 0; e < 8; ++e) o[e] = (short)f2bf(kq[e]);
  *reinterpret_cast<short8*>(&Ur[512 + lane * 8]) = o;
}

// ---------------- GEMM: BM=256 BN=128, 512 thr (bisect-exonerated R4 version) ----------------
// A k-range [0,1024) from U, [1024,1536) from h (x-part). res = h_in (bf16). out: bf16 h or f32.
template <bool LAST>
__global__ __launch_bounds__(512) void gemm_kernel(const unsigned short* __restrict__ U,
                                                   const unsigned short* __restrict__ hin,
                                                   const unsigned short* __restrict__ Bt,
                                                   const float* __restrict__ sc,
                                                   const float* __restrict__ sh,
                                                   unsigned short* __restrict__ hout,
                                                   float* __restrict__ fout) {
  constexpr int K = 1536;
  __shared__ short As[256 * 64];
  __shared__ short Bs[128 * 64];
  const int tid = threadIdx.x;
  const int wid = tid >> 6;          // 0..7
  const int lane = tid & 63;
  // XCD-affine mapping: 256 blocks; xcd = bid&7 owns m-panels [8*xcd, 8*xcd+8) x 4 n-blocks
  const int bid = blockIdx.x;
  const int xcd = bid & 7;
  const int i = bid >> 3;            // 0..31
  const int m0 = (xcd * 8 + (i >> 2)) * 256;
  const int n0 = (i & 3) * 128;
  const int wm = wid >> 1, wn = wid & 1;   // 4 x 2 waves, each 64x64 out
  const int lr = lane >> 4, lc = lane & 15;
  f32x4 acc[4][4] = {};

  for (int kt = 0; kt < K; kt += 64) {
    const unsigned short* asrc;
    int astr;
    if (kt < 1024) { asrc = U + kt; astr = 1024; }
    else           { asrc = hin + (kt - 1024); astr = 512; }
#pragma unroll
    for (int it = 0; it < 4; ++it) {   // A: 256 rows x 8 chunks = 2048 chunks
      const int wc0 = it * 512 + wid * 64;
      const int chunk = wc0 + lane;
      const int row = chunk >> 3, ck = chunk & 7;
      gload_lds16(asrc + (size_t)(m0 + row) * astr + ck * 8, &As[wc0 * 8]);
    }
#pragma unroll
    for (int it = 0; it < 2; ++it) {   // B: 128 rows x 8 chunks = 1024 chunks
      const int wc0 = it * 512 + wid * 64;
      const int chunk = wc0 + lane;
      const int row = chunk >> 3, ck = chunk & 7;
      gload_lds16(Bt + (size_t)(n0 + row) * K + kt + ck * 8, &Bs[wc0 * 8]);
    }
    __syncthreads();
#pragma unroll
    for (int kk = 0; kk < 64; kk += 32) {
      short8 af[4], bfr[4];
#pragma unroll
      for (int m = 0; m < 4; ++m)
        af[m] = *reinterpret_cast<const short8*>(&As[(wm * 64 + m * 16 + lc) * 64 + kk + lr * 8]);
#pragma unroll
      for (int n = 0; n < 4; ++n)
        bfr[n] = *reinterpret_cast<const short8*>(&Bs[(wn * 64 + n * 16 + lc) * 64 + kk + lr * 8]);
#pragma unroll
      for (int m = 0; m < 4; ++m)
#pragma unroll
        for (int n = 0; n < 4; ++n)
          acc[m][n] = mfma_bf16(af[m], bfr[n], acc[m][n]);
    }
    __syncthreads();
  }
#pragma unroll
  for (int n = 0; n < 4; ++n) {
    const int gcol = n0 + wn * 64 + n * 16 + lc;
    const float s = sc[gcol], t = sh[gcol];
#pragma unroll
    for (int m = 0; m < 4; ++m) {
#pragma unroll
      for (int r = 0; r < 4; ++r) {
        const int grow = m0 + wm * 64 + m * 16 + lr * 4 + r;  // D: row=(lane>>4)*4+reg, col=lane&15
        float v = acc[m][n][r] * s + t;
        v = v > 0.f ? v : 0.f;
        v += bf2f(hin[(size_t)grow * HID + gcol]);
        if (LAST)
          fout[(size_t)grow * HID + gcol] = v;
        else
          hout[(size_t)grow * HID + gcol] = f2bf(v);
      }
    }
  }
}

extern "C" void kernel_launch(void* const* d_in, const int* in_sizes, int n_in, void* d_out,
                              int out_size, void* d_ws, size_t ws_size, hipStream_t stream) {
  const float* ca = (const float*)d_in[1];
  const float* W1 = (const float*)d_in[3];
  const float* b1 = (const float*)d_in[4];
  const float* Wsl1 = (const float*)d_in[5];
  const float* bsl1 = (const float*)d_in[6];
  const float* Ws = (const float*)d_in[7];
  const float* bs = (const float*)d_in[8];
  const float* Wsls = (const float*)d_in[9];
  const float* bsls = (const float*)d_in[10];
  const float* gam = (const float*)d_in[11];
  const float* bet = (const float*)d_in[12];
  const float* mea = (const float*)d_in[13];
  const float* var = (const float*)d_in[14];
  float* out = (float*)d_out;

  char* ws = (char*)d_ws;
  size_t o = 0;
  auto alloc = [&](size_t bytes) {
    void* p = ws + o;
    o += (bytes + 255) & ~(size_t)255;
    return p;
  };
  float* cs = (float*)alloc((size_t)3 * NNODE * 4);
  int* knn = (int*)alloc((size_t)NEDGE * 4);
  int* cnt = (int*)alloc((size_t)NNODE * 4);
  int* roff = (int*)alloc((size_t)(NNODE + 1) * 4);
  int* rlist = (int*)alloc((size_t)NEDGE * 4);
  unsigned short* h0 = (unsigned short*)alloc((size_t)NNODE * HID * 2);
  unsigned short* h1 = (unsigned short*)alloc((size_t)NNODE * HID * 2);
  unsigned short* U = (unsigned short*)alloc((size_t)NNODE * 1024 * 2);
  unsigned short* Wcat = (unsigned short*)alloc((size_t)3 * 512 * 1536 * 2);
  float* sc = (float*)alloc(3 * 512 * 4);
  float* sh = (float*)alloc(3 * 512 * 4);

  hipMemsetAsync(cnt, 0, (size_t)NNODE * 4, stream);
  soa_kernel<<<NNODE / 256, 256, 0, stream>>>(ca, cs);
  knn_kernel<<<NNODE / 4, 256, 0, stream>>>(cs, knn);
  csr_count_kernel<<<NEDGE / 256, 256, 0, stream>>>(knn, cnt);
  csr_scan_kernel<<<1, 1024, 0, stream>>>(cnt, roff);
  hipMemsetAsync(cnt, 0, (size_t)NNODE * 4, stream);
  csr_fill_kernel<<<NEDGE / 256, 256, 0, stream>>>(knn, roff, cnt, rlist);
  layer1_kernel<<<NNODE / 4, 256, 0, stream>>>(ca, roff, rlist, W1, b1, Wsl1, bsl1, gam, bet, mea,
                                               var, h0);
  prep_weights_kernel<<<(3 * 512 * 1536 + 255) / 256, 256, 0, stream>>>(Ws, bs, Wsls, bsls, gam,
                                                                        bet, mea, var, Wcat, sc,
                                                                        sh);
  unsigned short* hin = h0;
  unsigned short* hout = h1;
  for (int l = 0; l < 3; ++l) {
    agg_kernel<<<NNODE / 4, 256, 0, stream>>>(hin, roff, rlist, U);
    const unsigned short* Bt = Wcat + (size_t)l * 512 * 1536;
    if (l == 2)
      gemm_kernel<true><<<256, 512, 0, stream>>>(U, hin, Bt, sc + l * 512, sh + l * 512, nullptr,
                                                 out);
    else
      gemm_kernel<false><<<256, 512, 0, stream>>>(U, hin, Bt, sc + l * 512, sh + l * 512, hout,
                                                  nullptr);
    unsigned short* tmp = hin; hin = hout; hout = tmp;
  }
}

// Round 7
// 344.266 us; speedup vs baseline: 1.1582x; 1.1582x over previous
//
#include <hip/hip_runtime.h>
#include <hip/hip_bf16.h>
#include <stdint.h>

#define LL 2048
#define BB 8
#define NNODE 16384           // BB*LL
#define HID 512
#define KNN_K 10
#define NEDGE (NNODE * KNN_K) // 163840
#define BN_EPS 1e-5f

typedef __attribute__((ext_vector_type(4))) float f32x4;
typedef __attribute__((ext_vector_type(8))) short short8;
typedef __attribute__((ext_vector_type(8))) __bf16 bf16x8;
typedef unsigned long long u64;

__device__ __forceinline__ unsigned short f2bf(float f) {
  unsigned u = __float_as_uint(f);
  u += 0x7FFFu + ((u >> 16) & 1u);   // RNE
  return (unsigned short)(u >> 16);
}
__device__ __forceinline__ float bf2f(unsigned short u) {
  return __uint_as_float(((unsigned)u) << 16);
}

__device__ __forceinline__ void gload_lds16(const void* g, void* l) {
  __builtin_amdgcn_global_load_lds((const __attribute__((address_space(1))) void*)g,
                                   (__attribute__((address_space(3))) void*)l, 16, 0, 0);
}

__device__ __forceinline__ f32x4 mfma_bf16(short8 a, short8 b, f32x4 c) {
  return __builtin_amdgcn_mfma_f32_16x16x32_bf16(
      __builtin_bit_cast(bf16x8, a), __builtin_bit_cast(bf16x8, b), c, 0, 0, 0);
}

// wave-wide min of u64 key: xor strides 1..16 via ds_swizzle (no addr VALU), 32 via shfl
__device__ __forceinline__ u64 wave_min_u64(u64 v) {
#define SWZ_STEP(pat)                                                   \
  {                                                                     \
    unsigned lo = (unsigned)v, hi = (unsigned)(v >> 32);                \
    unsigned slo = (unsigned)__builtin_amdgcn_ds_swizzle((int)lo, pat); \
    unsigned shi = (unsigned)__builtin_amdgcn_ds_swizzle((int)hi, pat); \
    u64 o = (((u64)shi) << 32) | slo;                                   \
    if (o < v) v = o;                                                   \
  }
  SWZ_STEP(0x041F)  // xor 1
  SWZ_STEP(0x081F)  // xor 2
  SWZ_STEP(0x101F)  // xor 4
  SWZ_STEP(0x201F)  // xor 8
  SWZ_STEP(0x401F)  // xor 16
#undef SWZ_STEP
  {
    u64 o = __shfl_xor(v, 32, 64);
    if (o < v) v = o;
  }
  return v;
}

// ---------------- coords AoS -> SoA ----------------
__global__ __launch_bounds__(256) void soa_kernel(const float* __restrict__ ca,
                                                  float* __restrict__ cs) {
  const int i = blockIdx.x * 256 + threadIdx.x;
  cs[i] = ca[(size_t)i * 3 + 0];
  cs[NNODE + i] = ca[(size_t)i * 3 + 1];
  cs[2 * NNODE + i] = ca[(size_t)i * 3 + 2];
}

// ---------------- kNN (R3-exact logic): 32 resident u64 keys; 10 extraction rounds ----------
// __launch_bounds__(256, 2): allow ~256 VGPR so key[32] (64 VGPRs) stays RESIDENT.
// R3/R6 measured VGPR=52 -> compiler rematerialized distances every round (66 us).
__global__ __launch_bounds__(256, 2) void knn_kernel(const float* __restrict__ cs,
                                                     int* __restrict__ knn_out) {
  const int node = blockIdx.x * 4 + (threadIdx.x >> 6);
  const int lane = threadIdx.x & 63;
  const int b = node >> 11;
  const int il = node & (LL - 1);
  const int boff = b << 11;
  const float* __restrict__ X = cs + boff;
  const float* __restrict__ Y = cs + NNODE + boff;
  const float* __restrict__ Z = cs + 2 * NNODE + boff;
  const float cx = X[il], cy = Y[il], cz = Z[il];
  u64 key[32];
#pragma unroll
  for (int jj = 0; jj < 32; ++jj) {
    const int j = jj * 64 + lane;
    // match numpy: ((dx^2 + dy^2) + dz^2), no fma contraction
    float dx = __fsub_rn(cx, X[j]);
    float dy = __fsub_rn(cy, Y[j]);
    float dz = __fsub_rn(cz, Z[j]);
    float s = __fmul_rn(dx, dx);
    s = __fadd_rn(s, __fmul_rn(dy, dy));
    s = __fadd_rn(s, __fmul_rn(dz, dz));
    key[jj] = (((u64)__float_as_uint(s)) << 32) | (unsigned)j;
  }
  // self has d2 == 0.0 exactly -> rank-0; start strictly after it.
  u64 last = (u64)(unsigned)il;
#pragma unroll 1
  for (int r = 0; r < KNN_K; ++r) {
    u64 b0 = ~0ull, b1 = ~0ull, b2 = ~0ull, b3 = ~0ull;
#pragma unroll
    for (int jj = 0; jj < 32; jj += 4) {
      { u64 k = key[jj + 0]; if (k > last && k < b0) b0 = k; }
      { u64 k = key[jj + 1]; if (k > last && k < b1) b1 = k; }
      { u64 k = key[jj + 2]; if (k > last && k < b2) b2 = k; }
      { u64 k = key[jj + 3]; if (k > last && k < b3) b3 = k; }
    }
    b0 = b0 < b1 ? b0 : b1;
    b2 = b2 < b3 ? b2 : b3;
    u64 best = wave_min_u64(b0 < b2 ? b0 : b2);
    if (lane == 0) knn_out[node * KNN_K + r] = boff + (int)(unsigned)best;
    last = best;
  }
}

// ---------------- reverse-CSR build (R3-exact) ----------------
__global__ void csr_count_kernel(const int* __restrict__ knn, int* __restrict__ cnt) {
  int e = blockIdx.x * 256 + threadIdx.x;
  atomicAdd(&cnt[knn[e]], 1);
}

__global__ __launch_bounds__(1024) void csr_scan_kernel(const int* __restrict__ cnt,
                                                        int* __restrict__ off) {
  __shared__ int part[1024];
  const int t = threadIdx.x;
  int loc[16];
  int s = 0;
#pragma unroll
  for (int k = 0; k < 16; ++k) { loc[k] = s; s += cnt[t * 16 + k]; }
  part[t] = s;
  __syncthreads();
  for (int d = 1; d < 1024; d <<= 1) {
    int v = (t >= d) ? part[t - d] : 0;
    __syncthreads();
    part[t] += v;
    __syncthreads();
  }
  int base = (t == 0) ? 0 : part[t - 1];
#pragma unroll
  for (int k = 0; k < 16; ++k) off[t * 16 + k] = base + loc[k];
  if (t == 1023) off[NNODE] = base + s;
}

__global__ void csr_fill_kernel(const int* __restrict__ knn, const int* __restrict__ off,
                                int* __restrict__ cur, int* __restrict__ lst) {
  int e = blockIdx.x * 256 + threadIdx.x;
  int dst = knn[e];
  int p = atomicAdd(&cur[dst], 1);
  lst[off[dst] + p] = e / KNN_K;   // src node (global id)
}

// ---------------- layer 1 (din=3): direct 9-wide dot, one wave per node; bf16 out ----------------
__global__ __launch_bounds__(256) void layer1_kernel(
    const float* __restrict__ ca, const int* __restrict__ roff, const int* __restrict__ rlist,
    const float* __restrict__ W1, const float* __restrict__ b1, const float* __restrict__ Wsl1,
    const float* __restrict__ bsl1, const float* __restrict__ gamma,
    const float* __restrict__ beta, const float* __restrict__ mean, const float* __restrict__ var,
    unsigned short* __restrict__ h) {
  const int node = blockIdx.x * 4 + (threadIdx.x >> 6);
  const int lane = threadIdx.x & 63;
  const int b = node >> 11;
  const int il = node & (LL - 1);
  const float* __restrict__ cb = ca + (size_t)b * LL * 3;
  float sx = 0, sy = 0, sz = 0;
#pragma unroll
  for (int d = -3; d <= 3; ++d) {
    if (d == 0) continue;
    int j = il + d;
    if ((unsigned)j < LL) { sx += cb[j * 3]; sy += cb[j * 3 + 1]; sz += cb[j * 3 + 2]; }
  }
  float kx = 0, ky = 0, kz = 0;
  const int e1 = roff[node + 1];
  for (int e = roff[node]; e < e1; ++e) {
    int si = rlist[e];
    kx += ca[si * 3]; ky += ca[si * 3 + 1]; kz += ca[si * 3 + 2];
  }
  const float xx = cb[il * 3], xy = cb[il * 3 + 1], xz = cb[il * 3 + 2];
#pragma unroll
  for (int r = 0; r < 8; ++r) {
    const int n = lane + 64 * r;
    const float* wr = W1 + n * 21;   // rel0 cols 0..2, rel2 cols 6..8
    const float* wsl = Wsl1 + n * 3;
    float acc = sx * wr[0] + sy * wr[1] + sz * wr[2] + kx * wr[6] + ky * wr[7] + kz * wr[8] +
                xx * wsl[0] + xy * wsl[1] + xz * wsl[2] + b1[n] + bsl1[n];
    float scl = gamma[n] * rsqrtf(var[n] + BN_EPS);
    float o2 = (acc - mean[n]) * scl + beta[n];
    h[(size_t)node * HID + n] = f2bf(o2 > 0.f ? o2 : 0.f);
  }
}

// ---------------- weight prep: Wcat = [W_rel0 | W_rel2 | Wsl] bf16, BN scale/shift ----------------
__global__ void prep_weights_kernel(const float* __restrict__ Ws, const float* __restrict__ bs,
                                    const float* __restrict__ Wsls, const float* __restrict__ bsls,
                                    const float* __restrict__ gam, const float* __restrict__ bet,
                                    const float* __restrict__ mea, const float* __restrict__ va,
                                    unsigned short* __restrict__ Wcat, float* __restrict__ sc,
                                    float* __restrict__ sh) {
  const int idx = blockIdx.x * 256 + threadIdx.x;
  if (idx >= 3 * 512 * 1536) return;
  const int l = idx / (512 * 1536);
  const int rem = idx - l * (512 * 1536);
  const int n = rem / 1536;
  const int k = rem - n * 1536;
  float v;
  if (k < 512)
    v = Ws[(size_t)l * 512 * 3584 + (size_t)n * 3584 + k];                // rel 0
  else if (k < 1024)
    v = Ws[(size_t)l * 512 * 3584 + (size_t)n * 3584 + 1024 + (k - 512)]; // rel 2
  else
    v = Wsls[(size_t)l * 512 * 512 + (size_t)n * 512 + (k - 1024)];       // self-loop
  Wcat[idx] = f2bf(v);
  if (k == 0) {
    const int g = (l + 1) * 512 + n;
    float s = gam[g] * rsqrtf(va[g] + BN_EPS);
    sc[l * 512 + n] = s;
    sh[l * 512 + n] = bet[g] + (bs[l * 512 + n] + bsls[l * 512 + n] - mea[g]) * s;
  }
}

// ---------------- aggregation: U[i] = [seq_sum | knn_sum] bf16 (x-part staged from h in gemm) ---
// XCD-affinity: batch b (2 MB h-slab) pinned to XCD b via blockIdx%8 -> gathers hit local L2.
__global__ __launch_bounds__(256) void agg_kernel(const unsigned short* __restrict__ hb,
                                                  const int* __restrict__ roff,
                                                  const int* __restrict__ rlist,
                                                  unsigned short* __restrict__ U) {
  const int g = blockIdx.x;   // 4096 blocks, 4 nodes each (one wave per node)
  const int node = ((g & 7) << 11) | ((g >> 3) << 2) | (threadIdx.x >> 6);
  const int lane = threadIdx.x & 63;
  const int b = node >> 11;
  const int il = node & (LL - 1);
  float sq[8] = {}, kq[8] = {};
  const int offs[6] = {-3, -2, -1, 1, 2, 3};
#pragma unroll
  for (int q = 0; q < 6; ++q) {
    int j = il + offs[q];
    if ((unsigned)j < LL) {
      short8 v = *reinterpret_cast<const short8*>(&hb[(size_t)(b * LL + j) * HID + lane * 8]);
#pragma unroll
      for (int e = 0; e < 8; ++e) sq[e] += bf2f((unsigned short)v[e]);
    }
  }
  const int e1 = roff[node + 1];
  for (int e = roff[node]; e < e1; ++e) {
    short8 v = *reinterpret_cast<const short8*>(&hb[(size_t)rlist[e] * HID + lane * 8]);
#pragma unroll
    for (int q = 0; q < 8; ++q) kq[q] += bf2f((unsigned short)v[q]);
  }
  unsigned short* Ur = U + (size_t)node * 1024;
  short8 o;
#pragma unroll
  for (int e = 0; e < 8; ++e) o[e] = (short)f2bf(sq[e]);
  *reinterpret_cast<short8*>(&Ur[lane * 8]) = o;
#pragma unroll
  for (int e = 0; e < 8; ++e) o[e] = (short)f2bf(kq[e]);
  *reinterpret_cast<short8*>(&Ur[512 + lane * 8]) = o;
}

// ---------------- GEMM (R3-exact known-good): 128x128 tile, 256 thr, 512 blocks ----------------
// A k-range [0,1024) from U, [1024,1536) from h (x-part). res = h_in (bf16). out: bf16 h or f32.
template <bool LAST>
__global__ __launch_bounds__(256) void gemm_kernel(const unsigned short* __restrict__ U,
                                                   const unsigned short* __restrict__ hin,
                                                   const unsigned short* __restrict__ Bt,
                                                   const float* __restrict__ sc,
                                                   const float* __restrict__ sh,
                                                   unsigned short* __restrict__ hout,
                                                   float* __restrict__ fout) {
  constexpr int K = 1536;
  __shared__ short As[128 * 64];
  __shared__ short Bs[128 * 64];
  const int tid = threadIdx.x;
  const int wid = tid >> 6;
  const int lane = tid & 63;
  // XCD-affine block mapping: 512 blocks; xcd = b&7 owns m-panels [16*xcd, 16*xcd+16) x all n
  const int bid = blockIdx.x;
  const int xcd = bid & 7;
  const int i = bid >> 3;          // 0..63
  const int m0 = (xcd * 16 + (i >> 2)) * 128;
  const int n0 = (i & 3) * 128;
  const int wm = wid >> 1, wn = wid & 1;
  const int lr = lane >> 4, lc = lane & 15;
  f32x4 acc[4][4] = {};

  for (int kt = 0; kt < K; kt += 64) {
    const unsigned short* asrc;
    int astr;
    if (kt < 1024) { asrc = U + kt; astr = 1024; }
    else           { asrc = hin + (kt - 1024); astr = 512; }
#pragma unroll
    for (int it = 0; it < 4; ++it) {
      const int wc0 = it * 256 + wid * 64;      // wave's first 16B chunk (linear LDS dest)
      const int chunk = wc0 + lane;
      const int row = chunk >> 3, ck = chunk & 7;
      gload_lds16(asrc + (size_t)(m0 + row) * astr + ck * 8, &As[wc0 * 8]);
      gload_lds16(Bt + (size_t)(n0 + row) * K + kt + ck * 8, &Bs[wc0 * 8]);
    }
    __syncthreads();
#pragma unroll
    for (int kk = 0; kk < 64; kk += 32) {
      short8 af[4], bfr[4];
#pragma unroll
      for (int m = 0; m < 4; ++m)
        af[m] = *reinterpret_cast<const short8*>(&As[(wm * 64 + m * 16 + lc) * 64 + kk + lr * 8]);
#pragma unroll
      for (int n = 0; n < 4; ++n)
        bfr[n] = *reinterpret_cast<const short8*>(&Bs[(wn * 64 + n * 16 + lc) * 64 + kk + lr * 8]);
#pragma unroll
      for (int m = 0; m < 4; ++m)
#pragma unroll
        for (int n = 0; n < 4; ++n)
          acc[m][n] = mfma_bf16(af[m], bfr[n], acc[m][n]);
    }
    __syncthreads();
  }
#pragma unroll
  for (int n = 0; n < 4; ++n) {
    const int gcol = n0 + wn * 64 + n * 16 + lc;
    const float s = sc[gcol], t = sh[gcol];
#pragma unroll
    for (int m = 0; m < 4; ++m) {
#pragma unroll
      for (int r = 0; r < 4; ++r) {
        const int grow = m0 + wm * 64 + m * 16 + lr * 4 + r;  // D: row=(lane>>4)*4+reg, col=lane&15
        float v = acc[m][n][r] * s + t;
        v = v > 0.f ? v : 0.f;
        v += bf2f(hin[(size_t)grow * HID + gcol]);
        if (LAST)
          fout[(size_t)grow * HID + gcol] = v;
        else
          hout[(size_t)grow * HID + gcol] = f2bf(v);
      }
    }
  }
}

extern "C" void kernel_launch(void* const* d_in, const int* in_sizes, int n_in, void* d_out,
                              int out_size, void* d_ws, size_t ws_size, hipStream_t stream) {
  const float* ca = (const float*)d_in[1];
  const float* W1 = (const float*)d_in[3];
  const float* b1 = (const float*)d_in[4];
  const float* Wsl1 = (const float*)d_in[5];
  const float* bsl1 = (const float*)d_in[6];
  const float* Ws = (const float*)d_in[7];
  const float* bs = (const float*)d_in[8];
  const float* Wsls = (const float*)d_in[9];
  const float* bsls = (const float*)d_in[10];
  const float* gam = (const float*)d_in[11];
  const float* bet = (const float*)d_in[12];
  const float* mea = (const float*)d_in[13];
  const float* var = (const float*)d_in[14];
  float* out = (float*)d_out;

  char* ws = (char*)d_ws;
  size_t o = 0;
  auto alloc = [&](size_t bytes) {
    void* p = ws + o;
    o += (bytes + 255) & ~(size_t)255;
    return p;
  };
  float* cs = (float*)alloc((size_t)3 * NNODE * 4);
  int* knn = (int*)alloc((size_t)NEDGE * 4);
  int* cnt = (int*)alloc((size_t)NNODE * 4);
  int* roff = (int*)alloc((size_t)(NNODE + 1) * 4);
  int* rlist = (int*)alloc((size_t)NEDGE * 4);
  unsigned short* h0 = (unsigned short*)alloc((size_t)NNODE * HID * 2);
  unsigned short* h1 = (unsigned short*)alloc((size_t)NNODE * HID * 2);
  unsigned short* U = (unsigned short*)alloc((size_t)NNODE * 1024 * 2);
  unsigned short* Wcat = (unsigned short*)alloc((size_t)3 * 512 * 1536 * 2);
  float* sc = (float*)alloc(3 * 512 * 4);
  float* sh = (float*)alloc(3 * 512 * 4);

  hipMemsetAsync(cnt, 0, (size_t)NNODE * 4, stream);
  soa_kernel<<<NNODE / 256, 256, 0, stream>>>(ca, cs);
  knn_kernel<<<NNODE / 4, 256, 0, stream>>>(cs, knn);
  csr_count_kernel<<<NEDGE / 256, 256, 0, stream>>>(knn, cnt);
  csr_scan_kernel<<<1, 1024, 0, stream>>>(cnt, roff);
  hipMemsetAsync(cnt, 0, (size_t)NNODE * 4, stream);
  csr_fill_kernel<<<NEDGE / 256, 256, 0, stream>>>(knn, roff, cnt, rlist);
  layer1_kernel<<<NNODE / 4, 256, 0, stream>>>(ca, roff, rlist, W1, b1, Wsl1, bsl1, gam, bet, mea,
                                               var, h0);
  prep_weights_kernel<<<(3 * 512 * 1536 + 255) / 256, 256, 0, stream>>>(Ws, bs, Wsls, bsls, gam,
                                                                        bet, mea, var, Wcat, sc,
                                                                        sh);
  unsigned short* hin = h0;
  unsigned short* hout = h1;
  for (int l = 0; l < 3; ++l) {
    agg_kernel<<<NNODE / 4, 256, 0, stream>>>(hin, roff, rlist, U);
    const unsigned short* Bt = Wcat + (size_t)l * 512 * 1536;
    if (l == 2)
      gemm_kernel<true><<<512, 256, 0, stream>>>(U, hin, Bt, sc + l * 512, sh + l * 512, nullptr,
                                                 out);
    else
      gemm_kernel<false><<<512, 256, 0, stream>>>(U, hin, Bt, sc + l * 512, sh + l * 512, hout,
                                                  nullptr);
    unsigned short* tmp = hin; hin = hout; hout = tmp;
  }
}

// Round 8
// 344.263 us; speedup vs baseline: 1.1582x; 1.0000x over previous
//
#include <hip/hip_runtime.h>
#include <hip/hip_bf16.h>
#include <stdint.h>

#define LL 2048
#define BB 8
#define NNODE 16384           // BB*LL
#define HID 512
#define KNN_K 10
#define NEDGE (NNODE * KNN_K) // 163840
#define BN_EPS 1e-5f

typedef __attribute__((ext_vector_type(4))) float f32x4;
typedef __attribute__((ext_vector_type(8))) short short8;
typedef __attribute__((ext_vector_type(8))) __bf16 bf16x8;
typedef unsigned long long u64;

__device__ __forceinline__ unsigned short f2bf(float f) {
  unsigned u = __float_as_uint(f);
  u += 0x7FFFu + ((u >> 16) & 1u);   // RNE
  return (unsigned short)(u >> 16);
}
__device__ __forceinline__ float bf2f(unsigned short u) {
  return __uint_as_float(((unsigned)u) << 16);
}

__device__ __forceinline__ void gload_lds16(const void* g, void* l) {
  __builtin_amdgcn_global_load_lds((const __attribute__((address_space(1))) void*)g,
                                   (__attribute__((address_space(3))) void*)l, 16, 0, 0);
}

__device__ __forceinline__ f32x4 mfma_bf16(short8 a, short8 b, f32x4 c) {
  return __builtin_amdgcn_mfma_f32_16x16x32_bf16(
      __builtin_bit_cast(bf16x8, a), __builtin_bit_cast(bf16x8, b), c, 0, 0, 0);
}

// wave-wide min of u64 key: xor strides 1..16 via ds_swizzle (no addr VALU), 32 via shfl
__device__ __forceinline__ u64 wave_min_u64(u64 v) {
#define SWZ_STEP(pat)                                                   \
  {                                                                     \
    unsigned lo = (unsigned)v, hi = (unsigned)(v >> 32);                \
    unsigned slo = (unsigned)__builtin_amdgcn_ds_swizzle((int)lo, pat); \
    unsigned shi = (unsigned)__builtin_amdgcn_ds_swizzle((int)hi, pat); \
    u64 o = (((u64)shi) << 32) | slo;                                   \
    if (o < v) v = o;                                                   \
  }
  SWZ_STEP(0x041F)  // xor 1
  SWZ_STEP(0x081F)  // xor 2
  SWZ_STEP(0x101F)  // xor 4
  SWZ_STEP(0x201F)  // xor 8
  SWZ_STEP(0x401F)  // xor 16
#undef SWZ_STEP
  {
    u64 o = __shfl_xor(v, 32, 64);
    if (o < v) v = o;
  }
  return v;
}

// ---------------- coords AoS -> SoA ----------------
__global__ __launch_bounds__(256) void soa_kernel(const float* __restrict__ ca,
                                                  float* __restrict__ cs) {
  const int i = blockIdx.x * 256 + threadIdx.x;
  cs[i] = ca[(size_t)i * 3 + 0];
  cs[NNODE + i] = ca[(size_t)i * 3 + 1];
  cs[2 * NNODE + i] = ca[(size_t)i * 3 + 2];
}

// ---------------- kNN: 32 resident f32 d2 per lane (asm-pinned), 11 argmin rounds ----------
// Pinning via empty asm makes d2v opaque -> compiler CANNOT rematerialize distances
// (R3/R6/R7 all chose remat: VGPR=52, ~4700 VALU/wave, 66 us).
// Ordering bit-identical to u64-key version: f32 compare == bit compare for d2>=0;
// ascending-jj scan with strict < == lowest index on ties; key reduce ties by global j.
__global__ __launch_bounds__(256, 2) void knn_kernel(const float* __restrict__ cs,
                                                     int* __restrict__ knn_out) {
  const int node = blockIdx.x * 4 + (threadIdx.x >> 6);
  const int lane = threadIdx.x & 63;
  const int b = node >> 11;
  const int il = node & (LL - 1);
  const int boff = b << 11;
  const float* __restrict__ X = cs + boff;
  const float* __restrict__ Y = cs + NNODE + boff;
  const float* __restrict__ Z = cs + 2 * NNODE + boff;
  const float cx = X[il], cy = Y[il], cz = Z[il];
  float d2v[32];
#pragma unroll
  for (int jj = 0; jj < 32; ++jj) {
    const int j = jj * 64 + lane;
    // match numpy: ((dx^2 + dy^2) + dz^2), no fma contraction
    float dx = __fsub_rn(cx, X[j]);
    float dy = __fsub_rn(cy, Y[j]);
    float dz = __fsub_rn(cz, Z[j]);
    float s = __fmul_rn(dx, dx);
    s = __fadd_rn(s, __fmul_rn(dy, dy));
    s = __fadd_rn(s, __fmul_rn(dz, dz));
    d2v[jj] = s;
  }
#pragma unroll
  for (int jj = 0; jj < 32; ++jj) asm volatile("" : "+v"(d2v[jj]));   // pin: no remat
  // round 0 extracts rank-0 (self, d2==0); rounds 1..10 emit the K neighbors.
#pragma unroll 1
  for (int r = 0; r < KNN_K + 1; ++r) {
    float mn = d2v[0];
    int mj = 0;
#pragma unroll
    for (int jj = 1; jj < 32; ++jj) {
      const bool c = d2v[jj] < mn;   // strict: lowest jj wins ties
      mn = c ? d2v[jj] : mn;
      mj = c ? jj : mj;
    }
    const u64 k = (((u64)__float_as_uint(mn)) << 32) | (unsigned)((mj << 6) | lane);
    const u64 g = wave_min_u64(k);
    const int jwin = (int)(unsigned)g;        // winning global index in [0,2048)
    if (lane == 0 && r > 0) knn_out[node * KNN_K + (r - 1)] = boff + jwin;
    const int wl = jwin & 63;
    const int wj = __builtin_amdgcn_readfirstlane(jwin >> 6);   // uniform slot id
#pragma unroll
    for (int jj = 0; jj < 32; ++jj)
      if (jj == wj && lane == wl) d2v[jj] = __builtin_huge_valf();   // winner clears slot
  }
}

// ---------------- reverse-CSR build (R6-exact) ----------------
__global__ void csr_count_kernel(const int* __restrict__ knn, int* __restrict__ cnt) {
  int e = blockIdx.x * 256 + threadIdx.x;
  atomicAdd(&cnt[knn[e]], 1);
}

__global__ __launch_bounds__(1024) void csr_scan_kernel(const int* __restrict__ cnt,
                                                        int* __restrict__ off) {
  __shared__ int part[1024];
  const int t = threadIdx.x;
  int loc[16];
  int s = 0;
#pragma unroll
  for (int k = 0; k < 16; ++k) { loc[k] = s; s += cnt[t * 16 + k]; }
  part[t] = s;
  __syncthreads();
  for (int d = 1; d < 1024; d <<= 1) {
    int v = (t >= d) ? part[t - d] : 0;
    __syncthreads();
    part[t] += v;
    __syncthreads();
  }
  int base = (t == 0) ? 0 : part[t - 1];
#pragma unroll
  for (int k = 0; k < 16; ++k) off[t * 16 + k] = base + loc[k];
  if (t == 1023) off[NNODE] = base + s;
}

__global__ void csr_fill_kernel(const int* __restrict__ knn, const int* __restrict__ off,
                                int* __restrict__ cur, int* __restrict__ lst) {
  int e = blockIdx.x * 256 + threadIdx.x;
  int dst = knn[e];
  int p = atomicAdd(&cur[dst], 1);
  lst[off[dst] + p] = e / KNN_K;   // src node (global id)
}

// ---------------- layer 1 (din=3): direct 9-wide dot, one wave per node; bf16 out ----------------
__global__ __launch_bounds__(256) void layer1_kernel(
    const float* __restrict__ ca, const int* __restrict__ roff, const int* __restrict__ rlist,
    const float* __restrict__ W1, const float* __restrict__ b1, const float* __restrict__ Wsl1,
    const float* __restrict__ bsl1, const float* __restrict__ gamma,
    const float* __restrict__ beta, const float* __restrict__ mean, const float* __restrict__ var,
    unsigned short* __restrict__ h) {
  const int node = blockIdx.x * 4 + (threadIdx.x >> 6);
  const int lane = threadIdx.x & 63;
  const int b = node >> 11;
  const int il = node & (LL - 1);
  const float* __restrict__ cb = ca + (size_t)b * LL * 3;
  float sx = 0, sy = 0, sz = 0;
#pragma unroll
  for (int d = -3; d <= 3; ++d) {
    if (d == 0) continue;
    int j = il + d;
    if ((unsigned)j < LL) { sx += cb[j * 3]; sy += cb[j * 3 + 1]; sz += cb[j * 3 + 2]; }
  }
  float kx = 0, ky = 0, kz = 0;
  const int e1 = roff[node + 1];
  for (int e = roff[node]; e < e1; ++e) {
    int si = rlist[e];
    kx += ca[si * 3]; ky += ca[si * 3 + 1]; kz += ca[si * 3 + 2];
  }
  const float xx = cb[il * 3], xy = cb[il * 3 + 1], xz = cb[il * 3 + 2];
#pragma unroll
  for (int r = 0; r < 8; ++r) {
    const int n = lane + 64 * r;
    const float* wr = W1 + n * 21;   // rel0 cols 0..2, rel2 cols 6..8
    const float* wsl = Wsl1 + n * 3;
    float acc = sx * wr[0] + sy * wr[1] + sz * wr[2] + kx * wr[6] + ky * wr[7] + kz * wr[8] +
                xx * wsl[0] + xy * wsl[1] + xz * wsl[2] + b1[n] + bsl1[n];
    float scl = gamma[n] * rsqrtf(var[n] + BN_EPS);
    float o2 = (acc - mean[n]) * scl + beta[n];
    h[(size_t)node * HID + n] = f2bf(o2 > 0.f ? o2 : 0.f);
  }
}

// ---------------- weight prep: Wcat = [W_rel0 | W_rel2 | Wsl] bf16, BN scale/shift ----------------
__global__ void prep_weights_kernel(const float* __restrict__ Ws, const float* __restrict__ bs,
                                    const float* __restrict__ Wsls, const float* __restrict__ bsls,
                                    const float* __restrict__ gam, const float* __restrict__ bet,
                                    const float* __restrict__ mea, const float* __restrict__ va,
                                    unsigned short* __restrict__ Wcat, float* __restrict__ sc,
                                    float* __restrict__ sh) {
  const int idx = blockIdx.x * 256 + threadIdx.x;
  if (idx >= 3 * 512 * 1536) return;
  const int l = idx / (512 * 1536);
  const int rem = idx - l * (512 * 1536);
  const int n = rem / 1536;
  const int k = rem - n * 1536;
  float v;
  if (k < 512)
    v = Ws[(size_t)l * 512 * 3584 + (size_t)n * 3584 + k];                // rel 0
  else if (k < 1024)
    v = Ws[(size_t)l * 512 * 3584 + (size_t)n * 3584 + 1024 + (k - 512)]; // rel 2
  else
    v = Wsls[(size_t)l * 512 * 512 + (size_t)n * 512 + (k - 1024)];       // self-loop
  Wcat[idx] = f2bf(v);
  if (k == 0) {
    const int g = (l + 1) * 512 + n;
    float s = gam[g] * rsqrtf(va[g] + BN_EPS);
    sc[l * 512 + n] = s;
    sh[l * 512 + n] = bet[g] + (bs[l * 512 + n] + bsls[l * 512 + n] - mea[g]) * s;
  }
}

// ---------------- aggregation: U[i] = [seq_sum | knn_sum] bf16 (x-part staged from h in gemm) ---
// XCD-affinity: batch b (2 MB h-slab) pinned to XCD b via blockIdx%8 -> gathers hit local L2.
__global__ __launch_bounds__(256) void agg_kernel(const unsigned short* __restrict__ hb,
                                                  const int* __restrict__ roff,
                                                  const int* __restrict__ rlist,
                                                  unsigned short* __restrict__ U) {
  const int g = blockIdx.x;   // 4096 blocks, 4 nodes each (one wave per node)
  const int node = ((g & 7) << 11) | ((g >> 3) << 2) | (threadIdx.x >> 6);
  const int lane = threadIdx.x & 63;
  const int b = node >> 11;
  const int il = node & (LL - 1);
  float sq[8] = {}, kq[8] = {};
  const int offs[6] = {-3, -2, -1, 1, 2, 3};
#pragma unroll
  for (int q = 0; q < 6; ++q) {
    int j = il + offs[q];
    if ((unsigned)j < LL) {
      short8 v = *reinterpret_cast<const short8*>(&hb[(size_t)(b * LL + j) * HID + lane * 8]);
#pragma unroll
      for (int e = 0; e < 8; ++e) sq[e] += bf2f((unsigned short)v[e]);
    }
  }
  const int e1 = roff[node + 1];
  for (int e = roff[node]; e < e1; ++e) {
    short8 v = *reinterpret_cast<const short8*>(&hb[(size_t)rlist[e] * HID + lane * 8]);
#pragma unroll
    for (int q = 0; q < 8; ++q) kq[q] += bf2f((unsigned short)v[q]);
  }
  unsigned short* Ur = U + (size_t)node * 1024;
  short8 o;
#pragma unroll
  for (int e = 0; e < 8; ++e) o[e] = (short)f2bf(sq[e]);
  *reinterpret_cast<short8*>(&Ur[lane * 8]) = o;
#pragma unroll
  for (int e = 0; e < 8; ++e) o[e] = (short)f2bf(kq[e]);
  *reinterpret_cast<short8*>(&Ur[512 + lane * 8]) = o;
}

// ---------------- GEMM (R3/R6-exact known-good): 128x128 tile, 256 thr, 512 blocks ----------------
// A k-range [0,1024) from U, [1024,1536) from h (x-part). res = h_in (bf16). out: bf16 h or f32.
template <bool LAST>
__global__ __launch_bounds__(256) void gemm_kernel(const unsigned short* __restrict__ U,
                                                   const unsigned short* __restrict__ hin,
                                                   const unsigned short* __restrict__ Bt,
                                                   const float* __restrict__ sc,
                                                   const float* __restrict__ sh,
                                                   unsigned short* __restrict__ hout,
                                                   float* __restrict__ fout) {
  constexpr int K = 1536;
  __shared__ short As[128 * 64];
  __shared__ short Bs[128 * 64];
  const int tid = threadIdx.x;
  const int wid = tid >> 6;
  const int lane = tid & 63;
  // XCD-affine block mapping: 512 blocks; xcd = b&7 owns m-panels [16*xcd, 16*xcd+16) x all n
  const int bid = blockIdx.x;
  const int xcd = bid & 7;
  const int i = bid >> 3;          // 0..63
  const int m0 = (xcd * 16 + (i >> 2)) * 128;
  const int n0 = (i & 3) * 128;
  const int wm = wid >> 1, wn = wid & 1;
  const int lr = lane >> 4, lc = lane & 15;
  f32x4 acc[4][4] = {};

  for (int kt = 0; kt < K; kt += 64) {
    const unsigned short* asrc;
    int astr;
    if (kt < 1024) { asrc = U + kt; astr = 1024; }
    else           { asrc = hin + (kt - 1024); astr = 512; }
#pragma unroll
    for (int it = 0; it < 4; ++it) {
      const int wc0 = it * 256 + wid * 64;      // wave's first 16B chunk (linear LDS dest)
      const int chunk = wc0 + lane;
      const int row = chunk >> 3, ck = chunk & 7;
      gload_lds16(asrc + (size_t)(m0 + row) * astr + ck * 8, &As[wc0 * 8]);
      gload_lds16(Bt + (size_t)(n0 + row) * K + kt + ck * 8, &Bs[wc0 * 8]);
    }
    __syncthreads();
#pragma unroll
    for (int kk = 0; kk < 64; kk += 32) {
      short8 af[4], bfr[4];
#pragma unroll
      for (int m = 0; m < 4; ++m)
        af[m] = *reinterpret_cast<const short8*>(&As[(wm * 64 + m * 16 + lc) * 64 + kk + lr * 8]);
#pragma unroll
      for (int n = 0; n < 4; ++n)
        bfr[n] = *reinterpret_cast<const short8*>(&Bs[(wn * 64 + n * 16 + lc) * 64 + kk + lr * 8]);
#pragma unroll
      for (int m = 0; m < 4; ++m)
#pragma unroll
        for (int n = 0; n < 4; ++n)
          acc[m][n] = mfma_bf16(af[m], bfr[n], acc[m][n]);
    }
    __syncthreads();
  }
#pragma unroll
  for (int n = 0; n < 4; ++n) {
    const int gcol = n0 + wn * 64 + n * 16 + lc;
    const float s = sc[gcol], t = sh[gcol];
#pragma unroll
    for (int m = 0; m < 4; ++m) {
#pragma unroll
      for (int r = 0; r < 4; ++r) {
        const int grow = m0 + wm * 64 + m * 16 + lr * 4 + r;  // D: row=(lane>>4)*4+reg, col=lane&15
        float v = acc[m][n][r] * s + t;
        v = v > 0.f ? v : 0.f;
        v += bf2f(hin[(size_t)grow * HID + gcol]);
        if (LAST)
          fout[(size_t)grow * HID + gcol] = v;
        else
          hout[(size_t)grow * HID + gcol] = f2bf(v);
      }
    }
  }
}

extern "C" void kernel_launch(void* const* d_in, const int* in_sizes, int n_in, void* d_out,
                              int out_size, void* d_ws, size_t ws_size, hipStream_t stream) {
  const float* ca = (const float*)d_in[1];
  const float* W1 = (const float*)d_in[3];
  const float* b1 = (const float*)d_in[4];
  const float* Wsl1 = (const float*)d_in[5];
  const float* bsl1 = (const float*)d_in[6];
  const float* Ws = (const float*)d_in[7];
  const float* bs = (const float*)d_in[8];
  const float* Wsls = (const float*)d_in[9];
  const float* bsls = (const float*)d_in[10];
  const float* gam = (const float*)d_in[11];
  const float* bet = (const float*)d_in[12];
  const float* mea = (const float*)d_in[13];
  const float* var = (const float*)d_in[14];
  float* out = (float*)d_out;

  char* ws = (char*)d_ws;
  size_t o = 0;
  auto alloc = [&](size_t bytes) {
    void* p = ws + o;
    o += (bytes + 255) & ~(size_t)255;
    return p;
  };
  float* cs = (float*)alloc((size_t)3 * NNODE * 4);
  int* knn = (int*)alloc((size_t)NEDGE * 4);
  int* cnt = (int*)alloc((size_t)NNODE * 4);
  int* roff = (int*)alloc((size_t)(NNODE + 1) * 4);
  int* rlist = (int*)alloc((size_t)NEDGE * 4);
  unsigned short* h0 = (unsigned short*)alloc((size_t)NNODE * HID * 2);
  unsigned short* h1 = (unsigned short*)alloc((size_t)NNODE * HID * 2);
  unsigned short* U = (unsigned short*)alloc((size_t)NNODE * 1024 * 2);
  unsigned short* Wcat = (unsigned short*)alloc((size_t)3 * 512 * 1536 * 2);
  float* sc = (float*)alloc(3 * 512 * 4);
  float* sh = (float*)alloc(3 * 512 * 4);

  hipMemsetAsync(cnt, 0, (size_t)NNODE * 4, stream);
  soa_kernel<<<NNODE / 256, 256, 0, stream>>>(ca, cs);
  knn_kernel<<<NNODE / 4, 256, 0, stream>>>(cs, knn);
  csr_count_kernel<<<NEDGE / 256, 256, 0, stream>>>(knn, cnt);
  csr_scan_kernel<<<1, 1024, 0, stream>>>(cnt, roff);
  hipMemsetAsync(cnt, 0, (size_t)NNODE * 4, stream);
  csr_fill_kernel<<<NEDGE / 256, 256, 0, stream>>>(knn, roff, cnt, rlist);
  layer1_kernel<<<NNODE / 4, 256, 0, stream>>>(ca, roff, rlist, W1, b1, Wsl1, bsl1, gam, bet, mea,
                                               var, h0);
  prep_weights_kernel<<<(3 * 512 * 1536 + 255) / 256, 256, 0, stream>>>(Ws, bs, Wsls, bsls, gam,
                                                                        bet, mea, var, Wcat, sc,
                                                                        sh);
  unsigned short* hin = h0;
  unsigned short* hout = h1;
  for (int l = 0; l < 3; ++l) {
    agg_kernel<<<NNODE / 4, 256, 0, stream>>>(hin, roff, rlist, U);
    const unsigned short* Bt = Wcat + (size_t)l * 512 * 1536;
    if (l == 2)
      gemm_kernel<true><<<512, 256, 0, stream>>>(U, hin, Bt, sc + l * 512, sh + l * 512, nullptr,
                                                 out);
    else
      gemm_kernel<false><<<512, 256, 0, stream>>>(U, hin, Bt, sc + l * 512, sh + l * 512, hout,
                                                  nullptr);
    unsigned short* tmp = hin; hin = hout; hout = tmp;
  }
}

// Round 13
// 344.056 us; speedup vs baseline: 1.1589x; 1.0006x over previous
//
#include <hip/hip_runtime.h>
#include <hip/hip_bf16.h>
#include <stdint.h>

#define LL 2048
#define BB 8
#define NNODE 16384           // BB*LL
#define HID 512
#define KNN_K 10
#define NEDGE (NNODE * KNN_K) // 163840
#define BN_EPS 1e-5f

typedef __attribute__((ext_vector_type(4))) float f32x4;
typedef __attribute__((ext_vector_type(8))) short short8;
typedef __attribute__((ext_vector_type(8))) __bf16 bf16x8;
typedef unsigned long long u64;

__device__ __forceinline__ unsigned short f2bf(float f) {
  unsigned u = __float_as_uint(f);
  u += 0x7FFFu + ((u >> 16) & 1u);   // RNE
  return (unsigned short)(u >> 16);
}
__device__ __forceinline__ float bf2f(unsigned short u) {
  return __uint_as_float(((unsigned)u) << 16);
}

__device__ __forceinline__ void gload_lds16(const void* g, void* l) {
  __builtin_amdgcn_global_load_lds((const __attribute__((address_space(1))) void*)g,
                                   (__attribute__((address_space(3))) void*)l, 16, 0, 0);
}

__device__ __forceinline__ f32x4 mfma_bf16(short8 a, short8 b, f32x4 c) {
  return __builtin_amdgcn_mfma_f32_16x16x32_bf16(
      __builtin_bit_cast(bf16x8, a), __builtin_bit_cast(bf16x8, b), c, 0, 0, 0);
}

// wave-wide min of u64 key: xor strides 1..16 via ds_swizzle (no addr VALU), 32 via shfl
__device__ __forceinline__ u64 wave_min_u64(u64 v) {
#define SWZ_STEP(pat)                                                   \
  {                                                                     \
    unsigned lo = (unsigned)v, hi = (unsigned)(v >> 32);                \
    unsigned slo = (unsigned)__builtin_amdgcn_ds_swizzle((int)lo, pat); \
    unsigned shi = (unsigned)__builtin_amdgcn_ds_swizzle((int)hi, pat); \
    u64 o = (((u64)shi) << 32) | slo;                                   \
    if (o < v) v = o;                                                   \
  }
  SWZ_STEP(0x041F)  // xor 1
  SWZ_STEP(0x081F)  // xor 2
  SWZ_STEP(0x101F)  // xor 4
  SWZ_STEP(0x201F)  // xor 8
  SWZ_STEP(0x401F)  // xor 16
#undef SWZ_STEP
  {
    u64 o = __shfl_xor(v, 32, 64);
    if (o < v) v = o;
  }
  return v;
}

// ---------------- coords AoS -> SoA ----------------
__global__ __launch_bounds__(256) void soa_kernel(const float* __restrict__ ca,
                                                  float* __restrict__ cs) {
  const int i = blockIdx.x * 256 + threadIdx.x;
  cs[i] = ca[(size_t)i * 3 + 0];
  cs[NNODE + i] = ca[(size_t)i * 3 + 1];
  cs[2 * NNODE + i] = ca[(size_t)i * 3 + 2];
}

// ---------------- kNN (R8-exact logic, PASSED at 344us): f32 d2[32] asm-pinned, 11 argmin
// rounds. ONLY change vs R8: lane-0 also counts the edge into cnt (csr_count fused; same
// global-atomicAdd primitive csr_fill uses). The extraction family R2/R3/R6/R7/R8 passed
// 5/5; all restructurings (R4,R5,R9-R12) failed 7/7 -> family frozen.
__global__ __launch_bounds__(256, 2) void knn_kernel(const float* __restrict__ cs,
                                                     int* __restrict__ knn_out,
                                                     int* __restrict__ cnt) {
  const int node = blockIdx.x * 4 + (threadIdx.x >> 6);
  const int lane = threadIdx.x & 63;
  const int b = node >> 11;
  const int il = node & (LL - 1);
  const int boff = b << 11;
  const float* __restrict__ X = cs + boff;
  const float* __restrict__ Y = cs + NNODE + boff;
  const float* __restrict__ Z = cs + 2 * NNODE + boff;
  const float cx = X[il], cy = Y[il], cz = Z[il];
  float d2v[32];
#pragma unroll
  for (int jj = 0; jj < 32; ++jj) {
    const int j = jj * 64 + lane;
    // match numpy: ((dx^2 + dy^2) + dz^2), no fma contraction
    float dx = __fsub_rn(cx, X[j]);
    float dy = __fsub_rn(cy, Y[j]);
    float dz = __fsub_rn(cz, Z[j]);
    float s = __fmul_rn(dx, dx);
    s = __fadd_rn(s, __fmul_rn(dy, dy));
    s = __fadd_rn(s, __fmul_rn(dz, dz));
    d2v[jj] = s;
  }
#pragma unroll
  for (int jj = 0; jj < 32; ++jj) asm volatile("" : "+v"(d2v[jj]));   // pin: no remat
  // round 0 extracts rank-0 (self, d2==0); rounds 1..10 emit the K neighbors.
#pragma unroll 1
  for (int r = 0; r < KNN_K + 1; ++r) {
    float mn = d2v[0];
    int mj = 0;
#pragma unroll
    for (int jj = 1; jj < 32; ++jj) {
      const bool c = d2v[jj] < mn;   // strict: lowest jj wins ties
      mn = c ? d2v[jj] : mn;
      mj = c ? jj : mj;
    }
    const u64 k = (((u64)__float_as_uint(mn)) << 32) | (unsigned)((mj << 6) | lane);
    const u64 g = wave_min_u64(k);
    const int jwin = (int)(unsigned)g;        // winning global index in [0,2048)
    if (lane == 0 && r > 0) {
      const int idx = boff + jwin;
      knn_out[node * KNN_K + (r - 1)] = idx;
      atomicAdd(&cnt[idx], 1);   // fused csr_count
    }
    const int wl = jwin & 63;
    const int wj = __builtin_amdgcn_readfirstlane(jwin >> 6);   // uniform slot id
#pragma unroll
    for (int jj = 0; jj < 32; ++jj)
      if (jj == wj && lane == wl) d2v[jj] = __builtin_huge_valf();   // winner clears slot
  }
}

// ---------------- reverse-CSR build (R8-exact) ----------------
__global__ __launch_bounds__(1024) void csr_scan_kernel(const int* __restrict__ cnt,
                                                        int* __restrict__ off) {
  __shared__ int part[1024];
  const int t = threadIdx.x;
  int loc[16];
  int s = 0;
#pragma unroll
  for (int k = 0; k < 16; ++k) { loc[k] = s; s += cnt[t * 16 + k]; }
  part[t] = s;
  __syncthreads();
  for (int d = 1; d < 1024; d <<= 1) {
    int v = (t >= d) ? part[t - d] : 0;
    __syncthreads();
    part[t] += v;
    __syncthreads();
  }
  int base = (t == 0) ? 0 : part[t - 1];
#pragma unroll
  for (int k = 0; k < 16; ++k) off[t * 16 + k] = base + loc[k];
  if (t == 1023) off[NNODE] = base + s;
}

__global__ void csr_fill_kernel(const int* __restrict__ knn, const int* __restrict__ off,
                                int* __restrict__ cur, int* __restrict__ lst) {
  int e = blockIdx.x * 256 + threadIdx.x;
  int dst = knn[e];
  int p = atomicAdd(&cur[dst], 1);
  lst[off[dst] + p] = e / KNN_K;   // src node (global id)
}

// ---------------- layer 1 (din=3): direct 9-wide dot, one wave per node; bf16 out ----------------
__global__ __launch_bounds__(256) void layer1_kernel(
    const float* __restrict__ ca, const int* __restrict__ roff, const int* __restrict__ rlist,
    const float* __restrict__ W1, const float* __restrict__ b1, const float* __restrict__ Wsl1,
    const float* __restrict__ bsl1, const float* __restrict__ gamma,
    const float* __restrict__ beta, const float* __restrict__ mean, const float* __restrict__ var,
    unsigned short* __restrict__ h) {
  const int node = blockIdx.x * 4 + (threadIdx.x >> 6);
  const int lane = threadIdx.x & 63;
  const int b = node >> 11;
  const int il = node & (LL - 1);
  const float* __restrict__ cb = ca + (size_t)b * LL * 3;
  float sx = 0, sy = 0, sz = 0;
#pragma unroll
  for (int d = -3; d <= 3; ++d) {
    if (d == 0) continue;
    int j = il + d;
    if ((unsigned)j < LL) { sx += cb[j * 3]; sy += cb[j * 3 + 1]; sz += cb[j * 3 + 2]; }
  }
  float kx = 0, ky = 0, kz = 0;
  const int e1 = roff[node + 1];
  for (int e = roff[node]; e < e1; ++e) {
    int si = rlist[e];
    kx += ca[si * 3]; ky += ca[si * 3 + 1]; kz += ca[si * 3 + 2];
  }
  const float xx = cb[il * 3], xy = cb[il * 3 + 1], xz = cb[il * 3 + 2];
#pragma unroll
  for (int r = 0; r < 8; ++r) {
    const int n = lane + 64 * r;
    const float* wr = W1 + n * 21;   // rel0 cols 0..2, rel2 cols 6..8
    const float* wsl = Wsl1 + n * 3;
    float acc = sx * wr[0] + sy * wr[1] + sz * wr[2] + kx * wr[6] + ky * wr[7] + kz * wr[8] +
                xx * wsl[0] + xy * wsl[1] + xz * wsl[2] + b1[n] + bsl1[n];
    float scl = gamma[n] * rsqrtf(var[n] + BN_EPS);
    float o2 = (acc - mean[n]) * scl + beta[n];
    h[(size_t)node * HID + n] = f2bf(o2 > 0.f ? o2 : 0.f);
  }
}

// ---------------- weight prep: Wcat = [W_rel0 | W_rel2 | Wsl] bf16, BN scale/shift ----------------
__global__ void prep_weights_kernel(const float* __restrict__ Ws, const float* __restrict__ bs,
                                    const float* __restrict__ Wsls, const float* __restrict__ bsls,
                                    const float* __restrict__ gam, const float* __restrict__ bet,
                                    const float* __restrict__ mea, const float* __restrict__ va,
                                    unsigned short* __restrict__ Wcat, float* __restrict__ sc,
                                    float* __restrict__ sh) {
  const int idx = blockIdx.x * 256 + threadIdx.x;
  if (idx >= 3 * 512 * 1536) return;
  const int l = idx / (512 * 1536);
  const int rem = idx - l * (512 * 1536);
  const int n = rem / 1536;
  const int k = rem - n * 1536;
  float v;
  if (k < 512)
    v = Ws[(size_t)l * 512 * 3584 + (size_t)n * 3584 + k];                // rel 0
  else if (k < 1024)
    v = Ws[(size_t)l * 512 * 3584 + (size_t)n * 3584 + 1024 + (k - 512)]; // rel 2
  else
    v = Wsls[(size_t)l * 512 * 512 + (size_t)n * 512 + (k - 1024)];       // self-loop
  Wcat[idx] = f2bf(v);
  if (k == 0) {
    const int g = (l + 1) * 512 + n;
    float s = gam[g] * rsqrtf(va[g] + BN_EPS);
    sc[l * 512 + n] = s;
    sh[l * 512 + n] = bet[g] + (bs[l * 512 + n] + bsls[l * 512 + n] - mea[g]) * s;
  }
}

// ---------------- aggregation: U[i] = [seq_sum | knn_sum] bf16 (x-part staged from h in gemm) ---
// XCD-affinity: batch b (2 MB h-slab) pinned to XCD b via blockIdx%8 -> gathers hit local L2.
__global__ __launch_bounds__(256) void agg_kernel(const unsigned short* __restrict__ hb,
                                                  const int* __restrict__ roff,
                                                  const int* __restrict__ rlist,
                                                  unsigned short* __restrict__ U) {
  const int g = blockIdx.x;   // 4096 blocks, 4 nodes each (one wave per node)
  const int node = ((g & 7) << 11) | ((g >> 3) << 2) | (threadIdx.x >> 6);
  const int lane = threadIdx.x & 63;
  const int b = node >> 11;
  const int il = node & (LL - 1);
  float sq[8] = {}, kq[8] = {};
  const int offs[6] = {-3, -2, -1, 1, 2, 3};
#pragma unroll
  for (int q = 0; q < 6; ++q) {
    int j = il + offs[q];
    if ((unsigned)j < LL) {
      short8 v = *reinterpret_cast<const short8*>(&hb[(size_t)(b * LL + j) * HID + lane * 8]);
#pragma unroll
      for (int e = 0; e < 8; ++e) sq[e] += bf2f((unsigned short)v[e]);
    }
  }
  const int e1 = roff[node + 1];
  for (int e = roff[node]; e < e1; ++e) {
    short8 v = *reinterpret_cast<const short8*>(&hb[(size_t)rlist[e] * HID + lane * 8]);
#pragma unroll
    for (int q = 0; q < 8; ++q) kq[q] += bf2f((unsigned short)v[q]);
  }
  unsigned short* Ur = U + (size_t)node * 1024;
  short8 o;
#pragma unroll
  for (int e = 0; e < 8; ++e) o[e] = (short)f2bf(sq[e]);
  *reinterpret_cast<short8*>(&Ur[lane * 8]) = o;
#pragma unroll
  for (int e = 0; e < 8; ++e) o[e] = (short)f2bf(kq[e]);
  *reinterpret_cast<short8*>(&Ur[512 + lane * 8]) = o;
}

// ---------------- GEMM (R3/R6/R8-exact known-good): 128x128 tile, 256 thr, 512 blocks ----------------
// A k-range [0,1024) from U, [1024,1536) from h (x-part). res = h_in (bf16). out: bf16 h or f32.
template <bool LAST>
__global__ __launch_bounds__(256) void gemm_kernel(const unsigned short* __restrict__ U,
                                                   const unsigned short* __restrict__ hin,
                                                   const unsigned short* __restrict__ Bt,
                                                   const float* __restrict__ sc,
                                                   const float* __restrict__ sh,
                                                   unsigned short* __restrict__ hout,
                                                   float* __restrict__ fout) {
  constexpr int K = 1536;
  __shared__ short As[128 * 64];
  __shared__ short Bs[128 * 64];
  const int tid = threadIdx.x;
  const int wid = tid >> 6;
  const int lane = tid & 63;
  // XCD-affine block mapping: 512 blocks; xcd = b&7 owns m-panels [16*xcd, 16*xcd+16) x all n
  const int bid = blockIdx.x;
  const int xcd = bid & 7;
  const int i = bid >> 3;          // 0..63
  const int m0 = (xcd * 16 + (i >> 2)) * 128;
  const int n0 = (i & 3) * 128;
  const int wm = wid >> 1, wn = wid & 1;
  const int lr = lane >> 4, lc = lane & 15;
  f32x4 acc[4][4] = {};

  for (int kt = 0; kt < K; kt += 64) {
    const unsigned short* asrc;
    int astr;
    if (kt < 1024) { asrc = U + kt; astr = 1024; }
    else           { asrc = hin + (kt - 1024); astr = 512; }
#pragma unroll
    for (int it = 0; it < 4; ++it) {
      const int wc0 = it * 256 + wid * 64;      // wave's first 16B chunk (linear LDS dest)
      const int chunk = wc0 + lane;
      const int row = chunk >> 3, ck = chunk & 7;
      gload_lds16(asrc + (size_t)(m0 + row) * astr + ck * 8, &As[wc0 * 8]);
      gload_lds16(Bt + (size_t)(n0 + row) * K + kt + ck * 8, &Bs[wc0 * 8]);
    }
    __syncthreads();
#pragma unroll
    for (int kk = 0; kk < 64; kk += 32) {
      short8 af[4], bfr[4];
#pragma unroll
      for (int m = 0; m < 4; ++m)
        af[m] = *reinterpret_cast<const short8*>(&As[(wm * 64 + m * 16 + lc) * 64 + kk + lr * 8]);
#pragma unroll
      for (int n = 0; n < 4; ++n)
        bfr[n] = *reinterpret_cast<const short8*>(&Bs[(wn * 64 + n * 16 + lc) * 64 + kk + lr * 8]);
#pragma unroll
      for (int m = 0; m < 4; ++m)
#pragma unroll
        for (int n = 0; n < 4; ++n)
          acc[m][n] = mfma_bf16(af[m], bfr[n], acc[m][n]);
    }
    __syncthreads();
  }
#pragma unroll
  for (int n = 0; n < 4; ++n) {
    const int gcol = n0 + wn * 64 + n * 16 + lc;
    const float s = sc[gcol], t = sh[gcol];
#pragma unroll
    for (int m = 0; m < 4; ++m) {
#pragma unroll
      for (int r = 0; r < 4; ++r) {
        const int grow = m0 + wm * 64 + m * 16 + lr * 4 + r;  // D: row=(lane>>4)*4+reg, col=lane&15
        float v = acc[m][n][r] * s + t;
        v = v > 0.f ? v : 0.f;
        v += bf2f(hin[(size_t)grow * HID + gcol]);
        if (LAST)
          fout[(size_t)grow * HID + gcol] = v;
        else
          hout[(size_t)grow * HID + gcol] = f2bf(v);
      }
    }
  }
}

extern "C" void kernel_launch(void* const* d_in, const int* in_sizes, int n_in, void* d_out,
                              int out_size, void* d_ws, size_t ws_size, hipStream_t stream) {
  const float* ca = (const float*)d_in[1];
  const float* W1 = (const float*)d_in[3];
  const float* b1 = (const float*)d_in[4];
  const float* Wsl1 = (const float*)d_in[5];
  const float* bsl1 = (const float*)d_in[6];
  const float* Ws = (const float*)d_in[7];
  const float* bs = (const float*)d_in[8];
  const float* Wsls = (const float*)d_in[9];
  const float* bsls = (const float*)d_in[10];
  const float* gam = (const float*)d_in[11];
  const float* bet = (const float*)d_in[12];
  const float* mea = (const float*)d_in[13];
  const float* var = (const float*)d_in[14];
  float* out = (float*)d_out;

  char* ws = (char*)d_ws;
  size_t o = 0;
  auto alloc = [&](size_t bytes) {
    void* p = ws + o;
    o += (bytes + 255) & ~(size_t)255;
    return p;
  };
  float* cs = (float*)alloc((size_t)3 * NNODE * 4);
  int* knn = (int*)alloc((size_t)NEDGE * 4);
  int* cnt = (int*)alloc((size_t)NNODE * 4);
  int* cur = (int*)alloc((size_t)NNODE * 4);
  int* roff = (int*)alloc((size_t)(NNODE + 1) * 4);
  int* rlist = (int*)alloc((size_t)NEDGE * 4);
  unsigned short* h0 = (unsigned short*)alloc((size_t)NNODE * HID * 2);
  unsigned short* h1 = (unsigned short*)alloc((size_t)NNODE * HID * 2);
  unsigned short* U = (unsigned short*)alloc((size_t)NNODE * 1024 * 2);
  unsigned short* Wcat = (unsigned short*)alloc((size_t)3 * 512 * 1536 * 2);
  float* sc = (float*)alloc(3 * 512 * 4);
  float* sh = (float*)alloc(3 * 512 * 4);

  hipMemsetAsync(cnt, 0, (size_t)NNODE * 4, stream);
  hipMemsetAsync(cur, 0, (size_t)NNODE * 4, stream);
  soa_kernel<<<NNODE / 256, 256, 0, stream>>>(ca, cs);
  knn_kernel<<<NNODE / 4, 256, 0, stream>>>(cs, knn, cnt);
  csr_scan_kernel<<<1, 1024, 0, stream>>>(cnt, roff);
  csr_fill_kernel<<<NEDGE / 256, 256, 0, stream>>>(knn, roff, cur, rlist);
  layer1_kernel<<<NNODE / 4, 256, 0, stream>>>(ca, roff, rlist, W1, b1, Wsl1, bsl1, gam, bet, mea,
                                               var, h0);
  prep_weights_kernel<<<(3 * 512 * 1536 + 255) / 256, 256, 0, stream>>>(Ws, bs, Wsls, bsls, gam,
                                                                        bet, mea, var, Wcat, sc,
                                                                        sh);
  unsigned short* hin = h0;
  unsigned short* hout = h1;
  for (int l = 0; l < 3; ++l) {
    agg_kernel<<<NNODE / 4, 256, 0, stream>>>(hin, roff, rlist, U);
    const unsigned short* Bt = Wcat + (size_t)l * 512 * 1536;
    if (l == 2)
      gemm_kernel<true><<<512, 256, 0, stream>>>(U, hin, Bt, sc + l * 512, sh + l * 512, nullptr,
                                                 out);
    else
      gemm_kernel<false><<<512, 256, 0, stream>>>(U, hin, Bt, sc + l * 512, sh + l * 512, hout,
                                                  nullptr);
    unsigned short* tmp = hin; hin = hout; hout = tmp;
  }
}

// Round 14
// 331.776 us; speedup vs baseline: 1.2018x; 1.0370x over previous
//
#include <hip/hip_runtime.h>
#include <hip/hip_bf16.h>
#include <stdint.h>

#define LL 2048
#define BB 8
#define NNODE 16384           // BB*LL
#define HID 512
#define KNN_K 10
#define NEDGE (NNODE * KNN_K) // 163840
#define BN_EPS 1e-5f

typedef __attribute__((ext_vector_type(4))) float f32x4;
typedef __attribute__((ext_vector_type(8))) short short8;
typedef __attribute__((ext_vector_type(8))) __bf16 bf16x8;
typedef unsigned long long u64;

__device__ __forceinline__ unsigned short f2bf(float f) {
  unsigned u = __float_as_uint(f);
  u += 0x7FFFu + ((u >> 16) & 1u);   // RNE
  return (unsigned short)(u >> 16);
}
__device__ __forceinline__ float bf2f(unsigned short u) {
  return __uint_as_float(((unsigned)u) << 16);
}

__device__ __forceinline__ void gload_lds16(const void* g, void* l) {
  __builtin_amdgcn_global_load_lds((const __attribute__((address_space(1))) void*)g,
                                   (__attribute__((address_space(3))) void*)l, 16, 0, 0);
}

__device__ __forceinline__ f32x4 mfma_bf16(short8 a, short8 b, f32x4 c) {
  return __builtin_amdgcn_mfma_f32_16x16x32_bf16(
      __builtin_bit_cast(bf16x8, a), __builtin_bit_cast(bf16x8, b), c, 0, 0, 0);
}

// wave-wide min of u64 key: xor strides 1..16 via ds_swizzle (no addr VALU), 32 via shfl
__device__ __forceinline__ u64 wave_min_u64(u64 v) {
#define SWZ_STEP(pat)                                                   \
  {                                                                     \
    unsigned lo = (unsigned)v, hi = (unsigned)(v >> 32);                \
    unsigned slo = (unsigned)__builtin_amdgcn_ds_swizzle((int)lo, pat); \
    unsigned shi = (unsigned)__builtin_amdgcn_ds_swizzle((int)hi, pat); \
    u64 o = (((u64)shi) << 32) | slo;                                   \
    if (o < v) v = o;                                                   \
  }
  SWZ_STEP(0x041F)  // xor 1
  SWZ_STEP(0x081F)  // xor 2
  SWZ_STEP(0x101F)  // xor 4
  SWZ_STEP(0x201F)  // xor 8
  SWZ_STEP(0x401F)  // xor 16
#undef SWZ_STEP
  {
    u64 o = __shfl_xor(v, 32, 64);
    if (o < v) v = o;
  }
  return v;
}

// ---------------- coords AoS -> SoA ----------------
__global__ __launch_bounds__(256) void soa_kernel(const float* __restrict__ ca,
                                                  float* __restrict__ cs) {
  const int i = blockIdx.x * 256 + threadIdx.x;
  cs[i] = ca[(size_t)i * 3 + 0];
  cs[NNODE + i] = ca[(size_t)i * 3 + 1];
  cs[2 * NNODE + i] = ca[(size_t)i * 3 + 2];
}

// ---------------- kNN (R13-exact, PASSED): f32 d2[32] asm-pinned, 11 argmin rounds,
// fused csr_count. Family frozen: extraction passed 5/5, restructurings failed 7/7.
__global__ __launch_bounds__(256, 2) void knn_kernel(const float* __restrict__ cs,
                                                     int* __restrict__ knn_out,
                                                     int* __restrict__ cnt) {
  const int node = blockIdx.x * 4 + (threadIdx.x >> 6);
  const int lane = threadIdx.x & 63;
  const int b = node >> 11;
  const int il = node & (LL - 1);
  const int boff = b << 11;
  const float* __restrict__ X = cs + boff;
  const float* __restrict__ Y = cs + NNODE + boff;
  const float* __restrict__ Z = cs + 2 * NNODE + boff;
  const float cx = X[il], cy = Y[il], cz = Z[il];
  float d2v[32];
#pragma unroll
  for (int jj = 0; jj < 32; ++jj) {
    const int j = jj * 64 + lane;
    // match numpy: ((dx^2 + dy^2) + dz^2), no fma contraction
    float dx = __fsub_rn(cx, X[j]);
    float dy = __fsub_rn(cy, Y[j]);
    float dz = __fsub_rn(cz, Z[j]);
    float s = __fmul_rn(dx, dx);
    s = __fadd_rn(s, __fmul_rn(dy, dy));
    s = __fadd_rn(s, __fmul_rn(dz, dz));
    d2v[jj] = s;
  }
#pragma unroll
  for (int jj = 0; jj < 32; ++jj) asm volatile("" : "+v"(d2v[jj]));   // pin: no remat
  // round 0 extracts rank-0 (self, d2==0); rounds 1..10 emit the K neighbors.
#pragma unroll 1
  for (int r = 0; r < KNN_K + 1; ++r) {
    float mn = d2v[0];
    int mj = 0;
#pragma unroll
    for (int jj = 1; jj < 32; ++jj) {
      const bool c = d2v[jj] < mn;   // strict: lowest jj wins ties
      mn = c ? d2v[jj] : mn;
      mj = c ? jj : mj;
    }
    const u64 k = (((u64)__float_as_uint(mn)) << 32) | (unsigned)((mj << 6) | lane);
    const u64 g = wave_min_u64(k);
    const int jwin = (int)(unsigned)g;        // winning global index in [0,2048)
    if (lane == 0 && r > 0) {
      const int idx = boff + jwin;
      knn_out[node * KNN_K + (r - 1)] = idx;
      atomicAdd(&cnt[idx], 1);   // fused csr_count
    }
    const int wl = jwin & 63;
    const int wj = __builtin_amdgcn_readfirstlane(jwin >> 6);   // uniform slot id
#pragma unroll
    for (int jj = 0; jj < 32; ++jj)
      if (jj == wj && lane == wl) d2v[jj] = __builtin_huge_valf();   // winner clears slot
  }
}

// ---------------- reverse-CSR build (R13-exact) ----------------
__global__ __launch_bounds__(1024) void csr_scan_kernel(const int* __restrict__ cnt,
                                                        int* __restrict__ off) {
  __shared__ int part[1024];
  const int t = threadIdx.x;
  int loc[16];
  int s = 0;
#pragma unroll
  for (int k = 0; k < 16; ++k) { loc[k] = s; s += cnt[t * 16 + k]; }
  part[t] = s;
  __syncthreads();
  for (int d = 1; d < 1024; d <<= 1) {
    int v = (t >= d) ? part[t - d] : 0;
    __syncthreads();
    part[t] += v;
    __syncthreads();
  }
  int base = (t == 0) ? 0 : part[t - 1];
#pragma unroll
  for (int k = 0; k < 16; ++k) off[t * 16 + k] = base + loc[k];
  if (t == 1023) off[NNODE] = base + s;
}

__global__ void csr_fill_kernel(const int* __restrict__ knn, const int* __restrict__ off,
                                int* __restrict__ cur, int* __restrict__ lst) {
  int e = blockIdx.x * 256 + threadIdx.x;
  int dst = knn[e];
  int p = atomicAdd(&cur[dst], 1);
  lst[off[dst] + p] = e / KNN_K;   // src node (global id)
}

// ---------------- layer 1 (din=3): 9-wide dot; knn gather batched 8-wide for MLP ----------------
__global__ __launch_bounds__(256) void layer1_kernel(
    const float* __restrict__ ca, const int* __restrict__ roff, const int* __restrict__ rlist,
    const float* __restrict__ W1, const float* __restrict__ b1, const float* __restrict__ Wsl1,
    const float* __restrict__ bsl1, const float* __restrict__ gamma,
    const float* __restrict__ beta, const float* __restrict__ mean, const float* __restrict__ var,
    unsigned short* __restrict__ h) {
  const int node = blockIdx.x * 4 + (threadIdx.x >> 6);
  const int lane = threadIdx.x & 63;
  const int b = node >> 11;
  const int il = node & (LL - 1);
  const float* __restrict__ cb = ca + (size_t)b * LL * 3;
  float sx = 0, sy = 0, sz = 0;
#pragma unroll
  for (int d = -3; d <= 3; ++d) {
    if (d == 0) continue;
    int j = il + d;
    if ((unsigned)j < LL) { sx += cb[j * 3]; sy += cb[j * 3 + 1]; sz += cb[j * 3 + 2]; }
  }
  float kx = 0, ky = 0, kz = 0;
  const int e0 = roff[node], e1 = roff[node + 1];
#pragma unroll 1
  for (int e = e0; e < e1; e += 8) {
    const int nb = e1 - e;
    int idx[8];
#pragma unroll
    for (int i = 0; i < 8; ++i) idx[i] = (i < nb) ? rlist[e + i] : -1;
    float gx[8], gy[8], gz[8];
#pragma unroll
    for (int i = 0; i < 8; ++i) {
      if (idx[i] >= 0) {
        gx[i] = ca[(size_t)idx[i] * 3 + 0];
        gy[i] = ca[(size_t)idx[i] * 3 + 1];
        gz[i] = ca[(size_t)idx[i] * 3 + 2];
      }
    }
#pragma unroll
    for (int i = 0; i < 8; ++i)
      if (idx[i] >= 0) { kx += gx[i]; ky += gy[i]; kz += gz[i]; }
  }
  const float xx = cb[il * 3], xy = cb[il * 3 + 1], xz = cb[il * 3 + 2];
#pragma unroll
  for (int r = 0; r < 8; ++r) {
    const int n = lane + 64 * r;
    const float* wr = W1 + n * 21;   // rel0 cols 0..2, rel2 cols 6..8
    const float* wsl = Wsl1 + n * 3;
    float acc = sx * wr[0] + sy * wr[1] + sz * wr[2] + kx * wr[6] + ky * wr[7] + kz * wr[8] +
                xx * wsl[0] + xy * wsl[1] + xz * wsl[2] + b1[n] + bsl1[n];
    float scl = gamma[n] * rsqrtf(var[n] + BN_EPS);
    float o2 = (acc - mean[n]) * scl + beta[n];
    h[(size_t)node * HID + n] = f2bf(o2 > 0.f ? o2 : 0.f);
  }
}

// ---------------- weight prep: Wcat = [W_rel0 | W_rel2 | Wsl] bf16, BN scale/shift ----------------
__global__ void prep_weights_kernel(const float* __restrict__ Ws, const float* __restrict__ bs,
                                    const float* __restrict__ Wsls, const float* __restrict__ bsls,
                                    const float* __restrict__ gam, const float* __restrict__ bet,
                                    const float* __restrict__ mea, const float* __restrict__ va,
                                    unsigned short* __restrict__ Wcat, float* __restrict__ sc,
                                    float* __restrict__ sh) {
  const int idx = blockIdx.x * 256 + threadIdx.x;
  if (idx >= 3 * 512 * 1536) return;
  const int l = idx / (512 * 1536);
  const int rem = idx - l * (512 * 1536);
  const int n = rem / 1536;
  const int k = rem - n * 1536;
  float v;
  if (k < 512)
    v = Ws[(size_t)l * 512 * 3584 + (size_t)n * 3584 + k];                // rel 0
  else if (k < 1024)
    v = Ws[(size_t)l * 512 * 3584 + (size_t)n * 3584 + 1024 + (k - 512)]; // rel 2
  else
    v = Wsls[(size_t)l * 512 * 512 + (size_t)n * 512 + (k - 1024)];       // self-loop
  Wcat[idx] = f2bf(v);
  if (k == 0) {
    const int g = (l + 1) * 512 + n;
    float s = gam[g] * rsqrtf(va[g] + BN_EPS);
    sc[l * 512 + n] = s;
    sh[l * 512 + n] = bet[g] + (bs[l * 512 + n] + bsls[l * 512 + n] - mea[g]) * s;
  }
}

// ---------------- aggregation: U[i] = [seq_sum | knn_sum] bf16; knn gather batched 8-wide ------
// MLP fix: load 8 edge indices first (independent), then 8 h-row gathers in flight,
// then accumulate in ascending-e order (arithmetic order unchanged vs R13).
// XCD-affinity: batch b (2 MB h-slab) pinned to XCD b via blockIdx%8.
__global__ __launch_bounds__(256) void agg_kernel(const unsigned short* __restrict__ hb,
                                                  const int* __restrict__ roff,
                                                  const int* __restrict__ rlist,
                                                  unsigned short* __restrict__ U) {
  const int g = blockIdx.x;   // 4096 blocks, 4 nodes each (one wave per node)
  const int node = ((g & 7) << 11) | ((g >> 3) << 2) | (threadIdx.x >> 6);
  const int lane = threadIdx.x & 63;
  const int b = node >> 11;
  const int il = node & (LL - 1);
  float sq[8] = {}, kq[8] = {};
  const int offs[6] = {-3, -2, -1, 1, 2, 3};
#pragma unroll
  for (int q = 0; q < 6; ++q) {
    int j = il + offs[q];
    if ((unsigned)j < LL) {
      short8 v = *reinterpret_cast<const short8*>(&hb[(size_t)(b * LL + j) * HID + lane * 8]);
#pragma unroll
      for (int e = 0; e < 8; ++e) sq[e] += bf2f((unsigned short)v[e]);
    }
  }
  const int e0 = roff[node], e1 = roff[node + 1];
#pragma unroll 1
  for (int e = e0; e < e1; e += 8) {
    const int nb = e1 - e;
    int idx[8];
#pragma unroll
    for (int i = 0; i < 8; ++i) idx[i] = (i < nb) ? rlist[e + i] : -1;
    short8 v[8];
#pragma unroll
    for (int i = 0; i < 8; ++i)
      if (idx[i] >= 0)
        v[i] = *reinterpret_cast<const short8*>(&hb[(size_t)idx[i] * HID + lane * 8]);
#pragma unroll
    for (int i = 0; i < 8; ++i)
      if (idx[i] >= 0) {
#pragma unroll
        for (int q = 0; q < 8; ++q) kq[q] += bf2f((unsigned short)v[i][q]);
      }
  }
  unsigned short* Ur = U + (size_t)node * 1024;
  short8 o;
#pragma unroll
  for (int e = 0; e < 8; ++e) o[e] = (short)f2bf(sq[e]);
  *reinterpret_cast<short8*>(&Ur[lane * 8]) = o;
#pragma unroll
  for (int e = 0; e < 8; ++e) o[e] = (short)f2bf(kq[e]);
  *reinterpret_cast<short8*>(&Ur[512 + lane * 8]) = o;
}

// ---------------- GEMM (R3/R6/R8-exact known-good): 128x128 tile, 256 thr, 512 blocks ----------------
// A k-range [0,1024) from U, [1024,1536) from h (x-part). res = h_in (bf16). out: bf16 h or f32.
template <bool LAST>
__global__ __launch_bounds__(256) void gemm_kernel(const unsigned short* __restrict__ U,
                                                   const unsigned short* __restrict__ hin,
                                                   const unsigned short* __restrict__ Bt,
                                                   const float* __restrict__ sc,
                                                   const float* __restrict__ sh,
                                                   unsigned short* __restrict__ hout,
                                                   float* __restrict__ fout) {
  constexpr int K = 1536;
  __shared__ short As[128 * 64];
  __shared__ short Bs[128 * 64];
  const int tid = threadIdx.x;
  const int wid = tid >> 6;
  const int lane = tid & 63;
  // XCD-affine block mapping: 512 blocks; xcd = b&7 owns m-panels [16*xcd, 16*xcd+16) x all n
  const int bid = blockIdx.x;
  const int xcd = bid & 7;
  const int i = bid >> 3;          // 0..63
  const int m0 = (xcd * 16 + (i >> 2)) * 128;
  const int n0 = (i & 3) * 128;
  const int wm = wid >> 1, wn = wid & 1;
  const int lr = lane >> 4, lc = lane & 15;
  f32x4 acc[4][4] = {};

  for (int kt = 0; kt < K; kt += 64) {
    const unsigned short* asrc;
    int astr;
    if (kt < 1024) { asrc = U + kt; astr = 1024; }
    else           { asrc = hin + (kt - 1024); astr = 512; }
#pragma unroll
    for (int it = 0; it < 4; ++it) {
      const int wc0 = it * 256 + wid * 64;      // wave's first 16B chunk (linear LDS dest)
      const int chunk = wc0 + lane;
      const int row = chunk >> 3, ck = chunk & 7;
      gload_lds16(asrc + (size_t)(m0 + row) * astr + ck * 8, &As[wc0 * 8]);
      gload_lds16(Bt + (size_t)(n0 + row) * K + kt + ck * 8, &Bs[wc0 * 8]);
    }
    __syncthreads();
#pragma unroll
    for (int kk = 0; kk < 64; kk += 32) {
      short8 af[4], bfr[4];
#pragma unroll
      for (int m = 0; m < 4; ++m)
        af[m] = *reinterpret_cast<const short8*>(&As[(wm * 64 + m * 16 + lc) * 64 + kk + lr * 8]);
#pragma unroll
      for (int n = 0; n < 4; ++n)
        bfr[n] = *reinterpret_cast<const short8*>(&Bs[(wn * 64 + n * 16 + lc) * 64 + kk + lr * 8]);
#pragma unroll
      for (int m = 0; m < 4; ++m)
#pragma unroll
        for (int n = 0; n < 4; ++n)
          acc[m][n] = mfma_bf16(af[m], bfr[n], acc[m][n]);
    }
    __syncthreads();
  }
#pragma unroll
  for (int n = 0; n < 4; ++n) {
    const int gcol = n0 + wn * 64 + n * 16 + lc;
    const float s = sc[gcol], t = sh[gcol];
#pragma unroll
    for (int m = 0; m < 4; ++m) {
#pragma unroll
      for (int r = 0; r < 4; ++r) {
        const int grow = m0 + wm * 64 + m * 16 + lr * 4 + r;  // D: row=(lane>>4)*4+reg, col=lane&15
        float v = acc[m][n][r] * s + t;
        v = v > 0.f ? v : 0.f;
        v += bf2f(hin[(size_t)grow * HID + gcol]);
        if (LAST)
          fout[(size_t)grow * HID + gcol] = v;
        else
          hout[(size_t)grow * HID + gcol] = f2bf(v);
      }
    }
  }
}

extern "C" void kernel_launch(void* const* d_in, const int* in_sizes, int n_in, void* d_out,
                              int out_size, void* d_ws, size_t ws_size, hipStream_t stream) {
  const float* ca = (const float*)d_in[1];
  const float* W1 = (const float*)d_in[3];
  const float* b1 = (const float*)d_in[4];
  const float* Wsl1 = (const float*)d_in[5];
  const float* bsl1 = (const float*)d_in[6];
  const float* Ws = (const float*)d_in[7];
  const float* bs = (const float*)d_in[8];
  const float* Wsls = (const float*)d_in[9];
  const float* bsls = (const float*)d_in[10];
  const float* gam = (const float*)d_in[11];
  const float* bet = (const float*)d_in[12];
  const float* mea = (const float*)d_in[13];
  const float* var = (const float*)d_in[14];
  float* out = (float*)d_out;

  char* ws = (char*)d_ws;
  size_t o = 0;
  auto alloc = [&](size_t bytes) {
    void* p = ws + o;
    o += (bytes + 255) & ~(size_t)255;
    return p;
  };
  float* cs = (float*)alloc((size_t)3 * NNODE * 4);
  int* knn = (int*)alloc((size_t)NEDGE * 4);
  int* cnt = (int*)alloc((size_t)NNODE * 4);
  int* cur = (int*)alloc((size_t)NNODE * 4);
  int* roff = (int*)alloc((size_t)(NNODE + 1) * 4);
  int* rlist = (int*)alloc((size_t)NEDGE * 4);
  unsigned short* h0 = (unsigned short*)alloc((size_t)NNODE * HID * 2);
  unsigned short* h1 = (unsigned short*)alloc((size_t)NNODE * HID * 2);
  unsigned short* U = (unsigned short*)alloc((size_t)NNODE * 1024 * 2);
  unsigned short* Wcat = (unsigned short*)alloc((size_t)3 * 512 * 1536 * 2);
  float* sc = (float*)alloc(3 * 512 * 4);
  float* sh = (float*)alloc(3 * 512 * 4);

  hipMemsetAsync(cnt, 0, (size_t)NNODE * 4, stream);
  hipMemsetAsync(cur, 0, (size_t)NNODE * 4, stream);
  soa_kernel<<<NNODE / 256, 256, 0, stream>>>(ca, cs);
  knn_kernel<<<NNODE / 4, 256, 0, stream>>>(cs, knn, cnt);
  csr_scan_kernel<<<1, 1024, 0, stream>>>(cnt, roff);
  csr_fill_kernel<<<NEDGE / 256, 256, 0, stream>>>(knn, roff, cur, rlist);
  layer1_kernel<<<NNODE / 4, 256, 0, stream>>>(ca, roff, rlist, W1, b1, Wsl1, bsl1, gam, bet, mea,
                                               var, h0);
  prep_weights_kernel<<<(3 * 512 * 1536 + 255) / 256, 256, 0, stream>>>(Ws, bs, Wsls, bsls, gam,
                                                                        bet, mea, var, Wcat, sc,
                                                                        sh);
  unsigned short* hin = h0;
  unsigned short* hout = h1;
  for (int l = 0; l < 3; ++l) {
    agg_kernel<<<NNODE / 4, 256, 0, stream>>>(hin, roff, rlist, U);
    const unsigned short* Bt = Wcat + (size_t)l * 512 * 1536;
    if (l == 2)
      gemm_kernel<true><<<512, 256, 0, stream>>>(U, hin, Bt, sc + l * 512, sh + l * 512, nullptr,
                                                 out);
    else
      gemm_kernel<false><<<512, 256, 0, stream>>>(U, hin, Bt, sc + l * 512, sh + l * 512, hout,
                                                  nullptr);
    unsigned short* tmp = hin; hin = hout; hout = tmp;
  }
}

// Round 15
// 319.623 us; speedup vs baseline: 1.2475x; 1.0380x over previous
//
#include <hip/hip_runtime.h>
#include <hip/hip_bf16.h>
#include <stdint.h>

#define LL 2048
#define BB 8
#define NNODE 16384           // BB*LL
#define HID 512
#define KNN_K 10
#define NEDGE (NNODE * KNN_K) // 163840
#define BN_EPS 1e-5f

typedef __attribute__((ext_vector_type(4))) float f32x4;
typedef __attribute__((ext_vector_type(8))) short short8;
typedef __attribute__((ext_vector_type(8))) __bf16 bf16x8;
typedef unsigned long long u64;

__device__ __forceinline__ unsigned short f2bf(float f) {
  unsigned u = __float_as_uint(f);
  u += 0x7FFFu + ((u >> 16) & 1u);   // RNE
  return (unsigned short)(u >> 16);
}
__device__ __forceinline__ float bf2f(unsigned short u) {
  return __uint_as_float(((unsigned)u) << 16);
}

__device__ __forceinline__ void gload_lds16(const void* g, void* l) {
  __builtin_amdgcn_global_load_lds((const __attribute__((address_space(1))) void*)g,
                                   (__attribute__((address_space(3))) void*)l, 16, 0, 0);
}

__device__ __forceinline__ f32x4 mfma_bf16(short8 a, short8 b, f32x4 c) {
  return __builtin_amdgcn_mfma_f32_16x16x32_bf16(
      __builtin_bit_cast(bf16x8, a), __builtin_bit_cast(bf16x8, b), c, 0, 0, 0);
}

// wave-wide min of u64 key: xor strides 1..16 via ds_swizzle (no addr VALU), 32 via shfl
__device__ __forceinline__ u64 wave_min_u64(u64 v) {
#define SWZ_STEP(pat)                                                   \
  {                                                                     \
    unsigned lo = (unsigned)v, hi = (unsigned)(v >> 32);                \
    unsigned slo = (unsigned)__builtin_amdgcn_ds_swizzle((int)lo, pat); \
    unsigned shi = (unsigned)__builtin_amdgcn_ds_swizzle((int)hi, pat); \
    u64 o = (((u64)shi) << 32) | slo;                                   \
    if (o < v) v = o;                                                   \
  }
  SWZ_STEP(0x041F)  // xor 1
  SWZ_STEP(0x081F)  // xor 2
  SWZ_STEP(0x101F)  // xor 4
  SWZ_STEP(0x201F)  // xor 8
  SWZ_STEP(0x401F)  // xor 16
#undef SWZ_STEP
  {
    u64 o = __shfl_xor(v, 32, 64);
    if (o < v) v = o;
  }
  return v;
}

// ---------------- coords AoS -> SoA ----------------
__global__ __launch_bounds__(256) void soa_kernel(const float* __restrict__ ca,
                                                  float* __restrict__ cs) {
  const int i = blockIdx.x * 256 + threadIdx.x;
  cs[i] = ca[(size_t)i * 3 + 0];
  cs[NNODE + i] = ca[(size_t)i * 3 + 1];
  cs[2 * NNODE + i] = ca[(size_t)i * 3 + 2];
}

// ---------------- kNN (R13 algorithm EXACT; d2 storage moved scratch -> LDS) ----------------
// R13/R14 counters: asm-pin put d2v in SCRATCH (5.76 MB writes + re-reads each round).
// Same extraction algorithm (family frozen), same ordering; only the d2 array's home
// changes to per-wave LDS [jj*64+lane] (bank = lane%32 -> 2 lanes/bank = conflict-free).
__global__ __launch_bounds__(256, 2) void knn_kernel(const float* __restrict__ cs,
                                                     int* __restrict__ knn_out,
                                                     int* __restrict__ cnt) {
  __shared__ float d2l[4][32 * 64];   // 32 KB/block, per-wave slabs
  const int w = threadIdx.x >> 6;
  const int node = blockIdx.x * 4 + w;
  const int lane = threadIdx.x & 63;
  const int b = node >> 11;
  const int il = node & (LL - 1);
  const int boff = b << 11;
  const float* __restrict__ X = cs + boff;
  const float* __restrict__ Y = cs + NNODE + boff;
  const float* __restrict__ Z = cs + 2 * NNODE + boff;
  const float cx = X[il], cy = Y[il], cz = Z[il];
#pragma unroll
  for (int jj = 0; jj < 32; ++jj) {
    const int j = jj * 64 + lane;
    // match numpy: ((dx^2 + dy^2) + dz^2), no fma contraction
    float dx = __fsub_rn(cx, X[j]);
    float dy = __fsub_rn(cy, Y[j]);
    float dz = __fsub_rn(cz, Z[j]);
    float s = __fmul_rn(dx, dx);
    s = __fadd_rn(s, __fmul_rn(dy, dy));
    s = __fadd_rn(s, __fmul_rn(dz, dz));
    d2l[w][jj * 64 + lane] = s;
  }
  // round 0 extracts rank-0 (self, d2==0); rounds 1..10 emit the K neighbors.
#pragma unroll 1
  for (int r = 0; r < KNN_K + 1; ++r) {
    float mn = d2l[w][lane];
    int mj = 0;
#pragma unroll
    for (int jj = 1; jj < 32; ++jj) {
      const float v = d2l[w][jj * 64 + lane];
      const bool c = v < mn;   // strict: lowest jj wins ties
      mn = c ? v : mn;
      mj = c ? jj : mj;
    }
    const u64 k = (((u64)__float_as_uint(mn)) << 32) | (unsigned)((mj << 6) | lane);
    const u64 g = wave_min_u64(k);
    const int jwin = (int)(unsigned)g;        // winning global index in [0,2048)
    if (lane == 0 && r > 0) {
      const int idx = boff + jwin;
      knn_out[node * KNN_K + (r - 1)] = idx;
      atomicAdd(&cnt[idx], 1);   // fused csr_count
    }
    const int wl = jwin & 63;
    const int wj = __builtin_amdgcn_readfirstlane(jwin >> 6);   // uniform slot id
    if (lane == wl) d2l[w][wj * 64 + wl] = __builtin_huge_valf();   // winner clears slot
  }
}

// ---------------- reverse-CSR build (R13-exact) ----------------
__global__ __launch_bounds__(1024) void csr_scan_kernel(const int* __restrict__ cnt,
                                                        int* __restrict__ off) {
  __shared__ int part[1024];
  const int t = threadIdx.x;
  int loc[16];
  int s = 0;
#pragma unroll
  for (int k = 0; k < 16; ++k) { loc[k] = s; s += cnt[t * 16 + k]; }
  part[t] = s;
  __syncthreads();
  for (int d = 1; d < 1024; d <<= 1) {
    int v = (t >= d) ? part[t - d] : 0;
    __syncthreads();
    part[t] += v;
    __syncthreads();
  }
  int base = (t == 0) ? 0 : part[t - 1];
#pragma unroll
  for (int k = 0; k < 16; ++k) off[t * 16 + k] = base + loc[k];
  if (t == 1023) off[NNODE] = base + s;
}

__global__ void csr_fill_kernel(const int* __restrict__ knn, const int* __restrict__ off,
                                int* __restrict__ cur, int* __restrict__ lst) {
  int e = blockIdx.x * 256 + threadIdx.x;
  int dst = knn[e];
  int p = atomicAdd(&cur[dst], 1);
  lst[off[dst] + p] = e / KNN_K;   // src node (global id)
}

// ---------------- layer 1 (din=3): 9-wide dot; knn gather batched 8-wide for MLP ----------------
__global__ __launch_bounds__(256) void layer1_kernel(
    const float* __restrict__ ca, const int* __restrict__ roff, const int* __restrict__ rlist,
    const float* __restrict__ W1, const float* __restrict__ b1, const float* __restrict__ Wsl1,
    const float* __restrict__ bsl1, const float* __restrict__ gamma,
    const float* __restrict__ beta, const float* __restrict__ mean, const float* __restrict__ var,
    unsigned short* __restrict__ h) {
  const int node = blockIdx.x * 4 + (threadIdx.x >> 6);
  const int lane = threadIdx.x & 63;
  const int b = node >> 11;
  const int il = node & (LL - 1);
  const float* __restrict__ cb = ca + (size_t)b * LL * 3;
  float sx = 0, sy = 0, sz = 0;
#pragma unroll
  for (int d = -3; d <= 3; ++d) {
    if (d == 0) continue;
    int j = il + d;
    if ((unsigned)j < LL) { sx += cb[j * 3]; sy += cb[j * 3 + 1]; sz += cb[j * 3 + 2]; }
  }
  float kx = 0, ky = 0, kz = 0;
  const int e0 = roff[node], e1 = roff[node + 1];
#pragma unroll 1
  for (int e = e0; e < e1; e += 8) {
    const int nb = e1 - e;
    int idx[8];
#pragma unroll
    for (int i = 0; i < 8; ++i) idx[i] = (i < nb) ? rlist[e + i] : -1;
    float gx[8], gy[8], gz[8];
#pragma unroll
    for (int i = 0; i < 8; ++i) {
      if (idx[i] >= 0) {
        gx[i] = ca[(size_t)idx[i] * 3 + 0];
        gy[i] = ca[(size_t)idx[i] * 3 + 1];
        gz[i] = ca[(size_t)idx[i] * 3 + 2];
      }
    }
#pragma unroll
    for (int i = 0; i < 8; ++i)
      if (idx[i] >= 0) { kx += gx[i]; ky += gy[i]; kz += gz[i]; }
  }
  const float xx = cb[il * 3], xy = cb[il * 3 + 1], xz = cb[il * 3 + 2];
#pragma unroll
  for (int r = 0; r < 8; ++r) {
    const int n = lane + 64 * r;
    const float* wr = W1 + n * 21;   // rel0 cols 0..2, rel2 cols 6..8
    const float* wsl = Wsl1 + n * 3;
    float acc = sx * wr[0] + sy * wr[1] + sz * wr[2] + kx * wr[6] + ky * wr[7] + kz * wr[8] +
                xx * wsl[0] + xy * wsl[1] + xz * wsl[2] + b1[n] + bsl1[n];
    float scl = gamma[n] * rsqrtf(var[n] + BN_EPS);
    float o2 = (acc - mean[n]) * scl + beta[n];
    h[(size_t)node * HID + n] = f2bf(o2 > 0.f ? o2 : 0.f);
  }
}

// ---------------- weight prep: Wcat = [W_rel0 | W_rel2 | Wsl] bf16, BN scale/shift ----------------
__global__ void prep_weights_kernel(const float* __restrict__ Ws, const float* __restrict__ bs,
                                    const float* __restrict__ Wsls, const float* __restrict__ bsls,
                                    const float* __restrict__ gam, const float* __restrict__ bet,
                                    const float* __restrict__ mea, const float* __restrict__ va,
                                    unsigned short* __restrict__ Wcat, float* __restrict__ sc,
                                    float* __restrict__ sh) {
  const int idx = blockIdx.x * 256 + threadIdx.x;
  if (idx >= 3 * 512 * 1536) return;
  const int l = idx / (512 * 1536);
  const int rem = idx - l * (512 * 1536);
  const int n = rem / 1536;
  const int k = rem - n * 1536;
  float v;
  if (k < 512)
    v = Ws[(size_t)l * 512 * 3584 + (size_t)n * 3584 + k];                // rel 0
  else if (k < 1024)
    v = Ws[(size_t)l * 512 * 3584 + (size_t)n * 3584 + 1024 + (k - 512)]; // rel 2
  else
    v = Wsls[(size_t)l * 512 * 512 + (size_t)n * 512 + (k - 1024)];       // self-loop
  Wcat[idx] = f2bf(v);
  if (k == 0) {
    const int g = (l + 1) * 512 + n;
    float s = gam[g] * rsqrtf(va[g] + BN_EPS);
    sc[l * 512 + n] = s;
    sh[l * 512 + n] = bet[g] + (bs[l * 512 + n] + bsls[l * 512 + n] - mea[g]) * s;
  }
}

// ---------------- aggregation: U[i] = [seq_sum | knn_sum] bf16; knn gather batched 8-wide ------
// XCD-affinity: batch b (2 MB h-slab) pinned to XCD b via blockIdx%8.
__global__ __launch_bounds__(256) void agg_kernel(const unsigned short* __restrict__ hb,
                                                  const int* __restrict__ roff,
                                                  const int* __restrict__ rlist,
                                                  unsigned short* __restrict__ U) {
  const int g = blockIdx.x;   // 4096 blocks, 4 nodes each (one wave per node)
  const int node = ((g & 7) << 11) | ((g >> 3) << 2) | (threadIdx.x >> 6);
  const int lane = threadIdx.x & 63;
  const int b = node >> 11;
  const int il = node & (LL - 1);
  float sq[8] = {}, kq[8] = {};
  const int offs[6] = {-3, -2, -1, 1, 2, 3};
#pragma unroll
  for (int q = 0; q < 6; ++q) {
    int j = il + offs[q];
    if ((unsigned)j < LL) {
      short8 v = *reinterpret_cast<const short8*>(&hb[(size_t)(b * LL + j) * HID + lane * 8]);
#pragma unroll
      for (int e = 0; e < 8; ++e) sq[e] += bf2f((unsigned short)v[e]);
    }
  }
  const int e0 = roff[node], e1 = roff[node + 1];
#pragma unroll 1
  for (int e = e0; e < e1; e += 8) {
    const int nb = e1 - e;
    int idx[8];
#pragma unroll
    for (int i = 0; i < 8; ++i) idx[i] = (i < nb) ? rlist[e + i] : -1;
    short8 v[8];
#pragma unroll
    for (int i = 0; i < 8; ++i)
      if (idx[i] >= 0)
        v[i] = *reinterpret_cast<const short8*>(&hb[(size_t)idx[i] * HID + lane * 8]);
#pragma unroll
    for (int i = 0; i < 8; ++i)
      if (idx[i] >= 0) {
#pragma unroll
        for (int q = 0; q < 8; ++q) kq[q] += bf2f((unsigned short)v[i][q]);
      }
  }
  unsigned short* Ur = U + (size_t)node * 1024;
  short8 o;
#pragma unroll
  for (int e = 0; e < 8; ++e) o[e] = (short)f2bf(sq[e]);
  *reinterpret_cast<short8*>(&Ur[lane * 8]) = o;
#pragma unroll
  for (int e = 0; e < 8; ++e) o[e] = (short)f2bf(kq[e]);
  *reinterpret_cast<short8*>(&Ur[512 + lane * 8]) = o;
}

// ---------------- GEMM (R3/R6/R8-exact known-good): 128x128 tile, 256 thr, 512 blocks ----------------
// A k-range [0,1024) from U, [1024,1536) from h (x-part). res = h_in (bf16). out: bf16 h or f32.
template <bool LAST>
__global__ __launch_bounds__(256) void gemm_kernel(const unsigned short* __restrict__ U,
                                                   const unsigned short* __restrict__ hin,
                                                   const unsigned short* __restrict__ Bt,
                                                   const float* __restrict__ sc,
                                                   const float* __restrict__ sh,
                                                   unsigned short* __restrict__ hout,
                                                   float* __restrict__ fout) {
  constexpr int K = 1536;
  __shared__ short As[128 * 64];
  __shared__ short Bs[128 * 64];
  const int tid = threadIdx.x;
  const int wid = tid >> 6;
  const int lane = tid & 63;
  // XCD-affine block mapping: 512 blocks; xcd = b&7 owns m-panels [16*xcd, 16*xcd+16) x all n
  const int bid = blockIdx.x;
  const int xcd = bid & 7;
  const int i = bid >> 3;          // 0..63
  const int m0 = (xcd * 16 + (i >> 2)) * 128;
  const int n0 = (i & 3) * 128;
  const int wm = wid >> 1, wn = wid & 1;
  const int lr = lane >> 4, lc = lane & 15;
  f32x4 acc[4][4] = {};

  for (int kt = 0; kt < K; kt += 64) {
    const unsigned short* asrc;
    int astr;
    if (kt < 1024) { asrc = U + kt; astr = 1024; }
    else           { asrc = hin + (kt - 1024); astr = 512; }
#pragma unroll
    for (int it = 0; it < 4; ++it) {
      const int wc0 = it * 256 + wid * 64;      // wave's first 16B chunk (linear LDS dest)
      const int chunk = wc0 + lane;
      const int row = chunk >> 3, ck = chunk & 7;
      gload_lds16(asrc + (size_t)(m0 + row) * astr + ck * 8, &As[wc0 * 8]);
      gload_lds16(Bt + (size_t)(n0 + row) * K + kt + ck * 8, &Bs[wc0 * 8]);
    }
    __syncthreads();
#pragma unroll
    for (int kk = 0; kk < 64; kk += 32) {
      short8 af[4], bfr[4];
#pragma unroll
      for (int m = 0; m < 4; ++m)
        af[m] = *reinterpret_cast<const short8*>(&As[(wm * 64 + m * 16 + lc) * 64 + kk + lr * 8]);
#pragma unroll
      for (int n = 0; n < 4; ++n)
        bfr[n] = *reinterpret_cast<const short8*>(&Bs[(wn * 64 + n * 16 + lc) * 64 + kk + lr * 8]);
#pragma unroll
      for (int m = 0; m < 4; ++m)
#pragma unroll
        for (int n = 0; n < 4; ++n)
          acc[m][n] = mfma_bf16(af[m], bfr[n], acc[m][n]);
    }
    __syncthreads();
  }
#pragma unroll
  for (int n = 0; n < 4; ++n) {
    const int gcol = n0 + wn * 64 + n * 16 + lc;
    const float s = sc[gcol], t = sh[gcol];
#pragma unroll
    for (int m = 0; m < 4; ++m) {
#pragma unroll
      for (int r = 0; r < 4; ++r) {
        const int grow = m0 + wm * 64 + m * 16 + lr * 4 + r;  // D: row=(lane>>4)*4+reg, col=lane&15
        float v = acc[m][n][r] * s + t;
        v = v > 0.f ? v : 0.f;
        v += bf2f(hin[(size_t)grow * HID + gcol]);
        if (LAST)
          fout[(size_t)grow * HID + gcol] = v;
        else
          hout[(size_t)grow * HID + gcol] = f2bf(v);
      }
    }
  }
}

extern "C" void kernel_launch(void* const* d_in, const int* in_sizes, int n_in, void* d_out,
                              int out_size, void* d_ws, size_t ws_size, hipStream_t stream) {
  const float* ca = (const float*)d_in[1];
  const float* W1 = (const float*)d_in[3];
  const float* b1 = (const float*)d_in[4];
  const float* Wsl1 = (const float*)d_in[5];
  const float* bsl1 = (const float*)d_in[6];
  const float* Ws = (const float*)d_in[7];
  const float* bs = (const float*)d_in[8];
  const float* Wsls = (const float*)d_in[9];
  const float* bsls = (const float*)d_in[10];
  const float* gam = (const float*)d_in[11];
  const float* bet = (const float*)d_in[12];
  const float* mea = (const float*)d_in[13];
  const float* var = (const float*)d_in[14];
  float* out = (float*)d_out;

  char* ws = (char*)d_ws;
  size_t o = 0;
  auto alloc = [&](size_t bytes) {
    void* p = ws + o;
    o += (bytes + 255) & ~(size_t)255;
    return p;
  };
  float* cs = (float*)alloc((size_t)3 * NNODE * 4);
  int* knn = (int*)alloc((size_t)NEDGE * 4);
  int* cnt = (int*)alloc((size_t)NNODE * 4);
  int* cur = (int*)alloc((size_t)NNODE * 4);
  int* roff = (int*)alloc((size_t)(NNODE + 1) * 4);
  int* rlist = (int*)alloc((size_t)NEDGE * 4);
  unsigned short* h0 = (unsigned short*)alloc((size_t)NNODE * HID * 2);
  unsigned short* h1 = (unsigned short*)alloc((size_t)NNODE * HID * 2);
  unsigned short* U = (unsigned short*)alloc((size_t)NNODE * 1024 * 2);
  unsigned short* Wcat = (unsigned short*)alloc((size_t)3 * 512 * 1536 * 2);
  float* sc = (float*)alloc(3 * 512 * 4);
  float* sh = (float*)alloc(3 * 512 * 4);

  hipMemsetAsync(cnt, 0, (size_t)NNODE * 4, stream);
  hipMemsetAsync(cur, 0, (size_t)NNODE * 4, stream);
  soa_kernel<<<NNODE / 256, 256, 0, stream>>>(ca, cs);
  knn_kernel<<<NNODE / 4, 256, 0, stream>>>(cs, knn, cnt);
  csr_scan_kernel<<<1, 1024, 0, stream>>>(cnt, roff);
  csr_fill_kernel<<<NEDGE / 256, 256, 0, stream>>>(knn, roff, cur, rlist);
  layer1_kernel<<<NNODE / 4, 256, 0, stream>>>(ca, roff, rlist, W1, b1, Wsl1, bsl1, gam, bet, mea,
                                               var, h0);
  prep_weights_kernel<<<(3 * 512 * 1536 + 255) / 256, 256, 0, stream>>>(Ws, bs, Wsls, bsls, gam,
                                                                        bet, mea, var, Wcat, sc,
                                                                        sh);
  unsigned short* hin = h0;
  unsigned short* hout = h1;
  for (int l = 0; l < 3; ++l) {
    agg_kernel<<<NNODE / 4, 256, 0, stream>>>(hin, roff, rlist, U);
    const unsigned short* Bt = Wcat + (size_t)l * 512 * 1536;
    if (l == 2)
      gemm_kernel<true><<<512, 256, 0, stream>>>(U, hin, Bt, sc + l * 512, sh + l * 512, nullptr,
                                                 out);
    else
      gemm_kernel<false><<<512, 256, 0, stream>>>(U, hin, Bt, sc + l * 512, sh + l * 512, hout,
                                                  nullptr);
    unsigned short* tmp = hin; hin = hout; hout = tmp;
  }
}